// Round 4
// baseline (324.906 us; speedup 1.0000x reference)
//
#include <hip/hip_runtime.h>
#include <math.h>

// Problem constants (fixed by reference): B=4, S=2048, D=512, H=8, R=8, dk=64
#define B_ 4
#define S_ 2048
#define D_ 512
#define H_ 8
#define R_ 8
#define DK_ 64
#define NEDGE (B_*H_*2*R_*S_)   // 1,048,576
#define EPB   (2*R_*S_)         // 32768 edges per (b,h)
#define ELLCAP 64               // max in-degree slots; Poisson(15) tail ~2e-8
#define ELLSTRIDE 72            // padded row stride (bank-spread + prefetch slack)
#define SCALE_ (1.0f/24.0f)     // 1/(3*sqrt(dk))

typedef __attribute__((ext_vector_type(8))) short bf16x8;
typedef __attribute__((ext_vector_type(8))) unsigned short ushort8_t;
typedef __attribute__((ext_vector_type(4))) float f32x4;

#define AS1q const __attribute__((address_space(1)))
#define AS3q __attribute__((address_space(3)))

__device__ inline unsigned short f2bf(float f) {
    unsigned u = __builtin_bit_cast(unsigned, f);
    u += 0x7fffu + ((u >> 16) & 1u);   // RNE (no NaN inputs here)
    return (unsigned short)(u >> 16);
}
__device__ inline float bf2f(unsigned short u) {
    return __builtin_bit_cast(float, ((unsigned)u) << 16);
}

// ---------------- fused prep: qkv + W converts ------------------------------
__global__ __launch_bounds__(256) void prep(
    const float* __restrict__ query, const float* __restrict__ key,
    const float* __restrict__ value,
    const float* __restrict__ Wq, const float* __restrict__ Wk,
    const float* __restrict__ Wv, const float* __restrict__ Wo,
    unsigned short* __restrict__ qc, unsigned short* __restrict__ kc,
    unsigned short* __restrict__ vc,
    unsigned short* __restrict__ wqb, unsigned short* __restrict__ wkb,
    unsigned short* __restrict__ wvb, unsigned short* __restrict__ wob)
{
    int bid = blockIdx.x;
    const float* x;
    unsigned short* y;
    size_t i;
    if (bid < 12288) {
        int z = bid >> 12;                 // 0..2
        x = (z == 0) ? query : (z == 1) ? key : value;
        y = (z == 0) ? qc : (z == 1) ? kc : vc;
        i = ((size_t)(bid & 4095) * 256 + threadIdx.x) * 4;
    } else {
        int r = bid - 12288;
        int z = r >> 8;                    // 0..3
        x = (z == 0) ? Wq : (z == 1) ? Wk : (z == 2) ? Wv : Wo;
        y = (z == 0) ? wqb : (z == 1) ? wkb : (z == 2) ? wvb : wob;
        i = ((size_t)(r & 255) * 256 + threadIdx.x) * 4;
    }
    float4 v = *(const float4*)&x[i];
    *(ushort4*)&y[i] = make_ushort4(f2bf(v.x), f2bf(v.y), f2bf(v.z), f2bf(v.w));
}

// ---------------- bf16 GEMM, m97-style: global_load_lds + XOR-swizzled LDS --
template<int TN>
__global__ __launch_bounds__(256) void gemm_bf16(
    const unsigned short* __restrict__ A0, const unsigned short* __restrict__ A1,
    const unsigned short* __restrict__ A2,
    const unsigned short* __restrict__ W0, const unsigned short* __restrict__ W1,
    const unsigned short* __restrict__ W2,
    const float* __restrict__ bi0, const float* __restrict__ bi1, const float* __restrict__ bi2,
    unsigned short* __restrict__ C0, unsigned short* __restrict__ C1,
    unsigned short* __restrict__ C2,
    float* __restrict__ Cf, int a_bhsd)
{
    constexpr int NFR = TN / 32;           // B frags per wave (4 or 2)
    __shared__ unsigned short As[128 * 64];
    __shared__ unsigned short Bs[TN * 64];
    const int z = blockIdx.z;
    const unsigned short* A = (z == 0) ? A0 : (z == 1) ? A1 : A2;
    const unsigned short* W = (z == 0) ? W0 : (z == 1) ? W1 : W2;
    const float* bias        = (z == 0) ? bi0 : (z == 1) ? bi1 : bi2;
    unsigned short* C        = (z == 0) ? C0 : (z == 1) ? C1 : C2;

    const int t    = threadIdx.x;
    const int lane = t & 63;
    const int w    = t >> 6;
    const int wm   = w >> 1, wn = w & 1;
    const int m0   = blockIdx.x * 128;
    const int n0   = blockIdx.y * TN;

    const int lr    = lane >> 3;           // row within 8-row stage chunk
    const int cglob = (lane & 7) ^ lr;     // swizzled global source chunk

    f32x4 acc[4][NFR] = {};

    for (int kk = 0; kk < D_; kk += 64) {
        #pragma unroll
        for (int i = 0; i < 4; ++i) {
            int rowl = w * 32 + i * 8;         // wave-uniform LDS row base
            int m = m0 + rowl + lr;
            const unsigned short* ga;
            if (a_bhsd) {
                int b = m >> 11, s = m & (S_ - 1), h = kk >> 6;
                ga = A + ((((size_t)b * H_ + h) * S_ + s) << 6) + cglob * 8;
            } else {
                ga = A + (size_t)m * D_ + kk + cglob * 8;
            }
            __builtin_amdgcn_global_load_lds((AS1q unsigned*)ga,
                (AS3q unsigned*)(As + rowl * 64), 16, 0, 0);
        }
        #pragma unroll
        for (int i = 0; i < TN / 32; ++i) {
            int rowl = w * (TN / 4) + i * 8;
            const unsigned short* gb =
                W + (size_t)(n0 + rowl + lr) * D_ + kk + cglob * 8;
            __builtin_amdgcn_global_load_lds((AS1q unsigned*)gb,
                (AS3q unsigned*)(Bs + rowl * 64), 16, 0, 0);
        }
        __syncthreads();

        #pragma unroll
        for (int ks = 0; ks < 64; ks += 32) {
            const int c0 = ks >> 3;            // 0 or 4
            bf16x8 af[4], bfr[NFR];
            #pragma unroll
            for (int mi = 0; mi < 4; ++mi) {
                int row = wm * 64 + mi * 16 + (lane & 15);
                int cp  = (c0 + (lane >> 4)) ^ (lane & 7);
                af[mi] = *(const bf16x8*)&As[row * 64 + cp * 8];
            }
            #pragma unroll
            for (int nj = 0; nj < NFR; ++nj) {
                int row = wn * (TN / 2) + nj * 16 + (lane & 15);
                int cp  = (c0 + (lane >> 4)) ^ (lane & 7);
                bfr[nj] = *(const bf16x8*)&Bs[row * 64 + cp * 8];
            }
            #pragma unroll
            for (int mi = 0; mi < 4; ++mi)
                #pragma unroll
                for (int nj = 0; nj < NFR; ++nj)
                    acc[mi][nj] = __builtin_amdgcn_mfma_f32_16x16x32_bf16(af[mi], bfr[nj], acc[mi][nj], 0, 0, 0);
        }
        __syncthreads();
    }

    // epilogue: C/D layout col = lane&15, row = (lane>>4)*4 + reg
    #pragma unroll
    for (int mi = 0; mi < 4; ++mi) {
        #pragma unroll
        for (int nj = 0; nj < NFR; ++nj) {
            #pragma unroll
            for (int r = 0; r < 4; ++r) {
                int m = m0 + wm * 64 + mi * 16 + (lane >> 4) * 4 + r;
                int n = n0 + wn * (TN / 2) + nj * 16 + (lane & 15);
                float val = acc[mi][nj][r] + bias[n];
                if (Cf) {
                    Cf[(size_t)m * D_ + n] = val;
                } else {
                    int b = m >> 11, s = m & (S_ - 1);
                    int h = n >> 6,  d = n & 63;
                    C[((((size_t)b * H_ + h) * S_ + s) << 6) + d] = f2bf(val);
                }
            }
        }
    }
}

// ---------------- rank-1 score-term tables via MFMA -------------------------
// qrk[node][r2] = (q[node].rel_k[h][r2])/24 ; rqk[node][r2] = (rel_q[h][r2].k[node])/24
__global__ __launch_bounds__(256) void rel_dots(
    const unsigned short* __restrict__ q, const unsigned short* __restrict__ k_,
    const float* __restrict__ rel_q, const float* __restrict__ rel_k,
    float* __restrict__ qrk, float* __restrict__ rqk)
{
    const int t    = threadIdx.x;
    const int lane = t & 63;
    const int w    = t >> 6;
    const int n0   = blockIdx.x * 128 + w * 32;   // wave's 32-node base (never crosses bh)
    const int h    = (n0 >> 11) & 7;
    const int r2   = lane & 15;
    const int ch   = lane >> 4;                   // 0..3: 8-elem k-chunk

    // B fragments for both k-halves, both tables (f32 -> bf16 in-register)
    bf16x8 bk2[2], bq2[2];
    #pragma unroll
    for (int ks = 0; ks < 2; ++ks) {
        const float* pk = rel_k + (((h << 4) + r2) << 6) + ks * 32 + ch * 8;
        const float* pq = rel_q + (((h << 4) + r2) << 6) + ks * 32 + ch * 8;
        f32x4 k0 = *(const f32x4*)pk, k1 = *(const f32x4*)(pk + 4);
        f32x4 q0 = *(const f32x4*)pq, q1 = *(const f32x4*)(pq + 4);
        bf16x8 bk, bq;
        #pragma unroll
        for (int i = 0; i < 4; ++i) {
            bk[i]     = (short)f2bf(k0[i]);
            bk[4 + i] = (short)f2bf(k1[i]);
            bq[i]     = (short)f2bf(q0[i]);
            bq[4 + i] = (short)f2bf(q1[i]);
        }
        bk2[ks] = bk; bq2[ks] = bq;
    }

    f32x4 aq[2] = {{0.f,0.f,0.f,0.f},{0.f,0.f,0.f,0.f}};
    f32x4 ak[2] = {{0.f,0.f,0.f,0.f},{0.f,0.f,0.f,0.f}};
    #pragma unroll
    for (int mi = 0; mi < 2; ++mi) {
        int m = n0 + mi * 16 + r2;               // A-frag row = lane&15
        #pragma unroll
        for (int ks = 0; ks < 2; ++ks) {
            bf16x8 aqf = *(const bf16x8*)&q [((size_t)m << 6) + ks * 32 + ch * 8];
            bf16x8 akf = *(const bf16x8*)&k_[((size_t)m << 6) + ks * 32 + ch * 8];
            aq[mi] = __builtin_amdgcn_mfma_f32_16x16x32_bf16(aqf, bk2[ks], aq[mi], 0, 0, 0);
            ak[mi] = __builtin_amdgcn_mfma_f32_16x16x32_bf16(akf, bq2[ks], ak[mi], 0, 0, 0);
        }
    }
    #pragma unroll
    for (int mi = 0; mi < 2; ++mi) {
        #pragma unroll
        for (int r = 0; r < 4; ++r) {
            int m = n0 + mi * 16 + (ch << 2) + r;
            qrk[((size_t)m << 4) + r2] = aq[mi][r] * SCALE_;
            rqk[((size_t)m << 4) + r2] = ak[mi][r] * SCALE_;
        }
    }
}

// ---------------- fused ELL-build + score+softmax+aggregate -----------------
// One block per (bh, 128-dst window). Scan: coalesced int2 reads, r2>=1 only;
// the scan now ALSO gathers the rank-1 score terms (qrk+rqk) for each claimed
// edge and stores per-edge tb in LDS (latency hidden in the scan flow), so the
// gather phase's L2-gather chain is gone. Gather: group-per-dst (no epilogue
// reduce), 2-deep software pipeline on the k/v L2 loads; validity folded into
// tb=-1e30 (exp -> 0).
__global__ __launch_bounds__(1024, 8) void attn_fused(
    const unsigned short* __restrict__ q, const unsigned short* __restrict__ k_,
    const unsigned short* __restrict__ v_,
    const float* __restrict__ qrk, const float* __restrict__ rqk,
    const float* __restrict__ rel_v,
    const int* __restrict__ start_nodes, const int* __restrict__ end_nodes,
    unsigned short* __restrict__ attn)
{
    __shared__ unsigned short ell[128 * ELLSTRIDE];   // 18 KB
    __shared__ float ell_tb[128 * ELLSTRIDE];         // 36.9 KB
    __shared__ int cnt[128];
    const int bi  = blockIdx.x;          // 512 blocks
    const int xcd = bi & 7;
    const int loc = bi >> 3;             // 0..63
    const int bh  = xcd * 4 + (loc >> 4);
    const int dlo = (loc & 15) << 7;     // 128-dst window base
    const int t   = threadIdx.x;

    if (t < 128) cnt[t] = 0;
    __syncthreads();

    const size_t node_base = ((size_t)bh << 11);
    const float* qrk_bh = qrk + (node_base << 4);
    const float* rqk_bh = rqk + (node_base << 4);

    // ---- scan phase: coalesced int2 read of this bh's edge lists ----
    const int base_idx = bh * (R_ * S_);
    for (int f = S_ + t * 2; f < EPB; f += 2048) {   // 15 iterations, r2>=1
        int r2 = f >> 11;
        int s  = f & (S_ - 1);                        // even
        int idx = base_idx + ((r2 & 7) << 11) + s;
        int2 sn2 = *(const int2*)&start_nodes[idx];
        int2 en2 = *(const int2*)&end_nodes[idx];
        #pragma unroll
        for (int u = 0; u < 2; ++u) {
            int sn = u ? sn2.y : sn2.x;
            if (sn == -1) continue;                   // padded edge
            int en = u ? en2.y : en2.x;
            int dst = (r2 < R_) ? en : sn;
            unsigned rel = (unsigned)(dst - dlo);
            if (rel < 128u) {
                int ki = (r2 < R_) ? sn : en;
                // rank-1 terms gathered here (latency hidden by scan flow)
                float tb = qrk_bh[((size_t)dst << 4) + r2]
                         + rqk_bh[((size_t)ki  << 4) + r2];
                int pos = atomicAdd(&cnt[rel], 1);
                if (pos < ELLCAP) {
                    ell[rel * ELLSTRIDE + pos]    = (unsigned short)((r2 << 11) | ki);
                    ell_tb[rel * ELLSTRIDE + pos] = tb;
                }
            }
        }
    }
    __syncthreads();

    // ---- gather phase: group g of wave w owns dst dlo + w*8 + g ----
    const int w    = t >> 6;
    const int lane = t & 63;
    const int g    = lane >> 3;          // group (dst) within wave
    const int sub  = lane & 7;           // dk chunk (8 elems)
    const int dl   = w * 8 + g;          // 0..127
    const int dst  = dlo + dl;
    const int h    = bh & 7;
    const float* rvh = rel_v + ((size_t)(h << 4) << 6);   // [16][64] f32

    ushort8_t q8 = *(const ushort8_t*)&q[((node_base + dst) << 6) + sub * 8];
    float qv[8];
    #pragma unroll
    for (int i = 0; i < 8; ++i) qv[i] = bf2f(q8[i]);

    int n = cnt[dl];
    if (n > ELLCAP) n = ELLCAP;
    int nmax = n;
    nmax = max(nmax, __shfl_xor(nmax, 8));
    nmax = max(nmax, __shfl_xor(nmax, 16));
    nmax = max(nmax, __shfl_xor(nmax, 32));

    const unsigned short* er  = &ell[dl * ELLSTRIDE];
    const float*          etb = &ell_tb[dl * ELLSTRIDE];

    float den = 0.f;
    float o[8] = {};

    // stage issue: edge j -> regs (er row padded to 72, safe up to j=nmax+2)
    auto issue = [&](int j, ushort8_t& k8o, ushort8_t& v8o, float& tbo, int& r2o) {
        int d  = er[j];
        int ki = d & (S_ - 1);
        r2o = (d >> 11) & 15;
        k8o = *(const ushort8_t*)&k_[((node_base + ki) << 6) + sub * 8];
        v8o = *(const ushort8_t*)&v_[((node_base + ki) << 6) + sub * 8];
        tbo = (j < n) ? etb[j] : -1e30f;   // invalid -> exp() == 0
    };
    auto compute = [&](ushort8_t k8, ushort8_t v8, float tb, int r2) {
        float p = 0.f;
        #pragma unroll
        for (int i = 0; i < 8; ++i)
            p = fmaf(bf2f(k8[i]), qv[i], p);
        p += __shfl_xor(p, 1);
        p += __shfl_xor(p, 2);
        p += __shfl_xor(p, 4);
        float sf = __expf(fmaf(p, SCALE_, tb));
        const float* rvp = rvh + (r2 << 6) + sub * 8;
        f32x4 rv0 = *(const f32x4*)rvp;
        f32x4 rv1 = *(const f32x4*)(rvp + 4);
        den += sf;
        #pragma unroll
        for (int i = 0; i < 4; ++i)
            o[i] = fmaf(sf, bf2f(v8[i]) + rv0[i], o[i]);
        #pragma unroll
        for (int i = 0; i < 4; ++i)
            o[4 + i] = fmaf(sf, bf2f(v8[4 + i]) + rv1[i], o[4 + i]);
    };

    ushort8_t kA, vA, kB, vB;
    float tbA, tbB;
    int rA, rB;
    issue(0, kA, vA, tbA, rA);
    issue(1, kB, vB, tbB, rB);

    for (int j = 0; j < nmax; j += 2) {
        ushort8_t kC, vC, kD, vD;
        float tbC, tbD;
        int rC, rD;
        issue(j + 2, kC, vC, tbC, rC);
        issue(j + 3, kD, vD, tbD, rD);
        compute(kA, vA, tbA, rA);
        compute(kB, vB, tbB, rB);
        kA = kC; vA = vC; tbA = tbC; rA = rC;
        kB = kD; vB = vD; tbB = tbD; rB = rD;
    }

    // epilogue: den/o complete per-lane (sf uniform in-group), no reduce
    float inv = (den > 0.f) ? 1.0f / den : 0.f;
    ushort8_t r;
    #pragma unroll
    for (int i = 0; i < 8; ++i) r[i] = f2bf(o[i] * inv);
    *(ushort8_t*)&attn[((node_base + dst) << 6) + sub * 8] = r;
}

extern "C" void kernel_launch(void* const* d_in, const int* in_sizes, int n_in,
                              void* d_out, int out_size, void* d_ws, size_t ws_size,
                              hipStream_t stream) {
    const float* query = (const float*)d_in[0];
    const float* key   = (const float*)d_in[1];
    const float* value = (const float*)d_in[2];
    const int* start_nodes = (const int*)d_in[3];
    const int* end_nodes   = (const int*)d_in[4];
    const float* rel_q = (const float*)d_in[5];
    const float* rel_k = (const float*)d_in[6];
    const float* rel_v = (const float*)d_in[7];
    const float* Wq = (const float*)d_in[8];
    const float* bq = (const float*)d_in[9];
    const float* Wk = (const float*)d_in[10];
    const float* bk = (const float*)d_in[11];
    const float* Wv = (const float*)d_in[12];
    const float* bv = (const float*)d_in[13];
    const float* Wo = (const float*)d_in[14];
    const float* bo = (const float*)d_in[15];
    float* out = (float*)d_out;

    const size_t NQ = (size_t)B_ * H_ * S_ * DK_;   // 4,194,304
    const size_t NW = (size_t)D_ * D_;              // 262,144
    unsigned short* p = (unsigned short*)d_ws;
    unsigned short* qc = p;            p += NQ;
    unsigned short* kc = p;            p += NQ;
    unsigned short* vc = p;            p += NQ;
    unsigned short* q  = p;            p += NQ;
    unsigned short* k  = p;            p += NQ;
    unsigned short* v  = p;            p += NQ;
    unsigned short* attn = p;          p += NQ;
    unsigned short* wqb = p;           p += NW;
    unsigned short* wkb = p;           p += NW;
    unsigned short* wvb = p;           p += NW;
    unsigned short* wob = p;           p += NW;
    // score-term tables alias qc (dead after GEMM1): 2 x 1M f32 = 8 MB = |qc|
    float* qrk = (float*)qc;
    float* rqk = qrk + ((size_t)1 << 20);

    // 1) fused converts (one dispatch)
    prep<<<13312, 256, 0, stream>>>(query, key, value, Wq, Wk, Wv, Wo,
                                    qc, kc, vc, wqb, wkb, wvb, wob);

    // 2) fused QKV projection (128x128 tiles, 768 blocks)
    dim3 ggrid(B_ * S_ / 128, D_ / 128, 3);
    gemm_bf16<128><<<ggrid, 256, 0, stream>>>(qc, kc, vc, wqb, wkb, wvb, bq, bk, bv,
                                              q, k, v, nullptr, 0);

    // 3) rank-1 score-term tables via MFMA (q.rel_k, rel_q.k), prescaled by 1/24
    rel_dots<<<512, 256, 0, stream>>>(q, k, rel_q, rel_k, qrk, rqk);

    // 4) fused ELL-build + attention (no global ELL)
    attn_fused<<<512, 1024, 0, stream>>>(q, k, v, qrk, rqk, rel_v,
                                         start_nodes, end_nodes, attn);

    // 5) output projection (128x64 tiles -> 512 blocks = 2/CU, fp32 out)
    dim3 ogrid(B_ * S_ / 128, D_ / 64, 1);
    gemm_bf16<64><<<ogrid, 256, 0, stream>>>(attn, attn, attn, wob, wob, wob, bo, bo, bo,
                                             nullptr, nullptr, nullptr, out, 1);
}

// Round 5
// 219.973 us; speedup vs baseline: 1.4770x; 1.4770x over previous
//
#include <hip/hip_runtime.h>
#include <math.h>

// Problem constants (fixed by reference): B=4, S=2048, D=512, H=8, R=8, dk=64
#define B_ 4
#define S_ 2048
#define D_ 512
#define H_ 8
#define R_ 8
#define DK_ 64
#define NEDGE (B_*H_*2*R_*S_)   // 1,048,576
#define EPB   (2*R_*S_)         // 32768 edges per (b,h)
#define ELLCAP 64               // max in-degree slots; Poisson(15) tail ~2e-8
#define ELLSTRIDE 72            // padded row stride (bank-spread + prefetch slack)
#define SCALE_ (1.0f/24.0f)     // 1/(3*sqrt(dk))

typedef __attribute__((ext_vector_type(8))) short bf16x8;
typedef __attribute__((ext_vector_type(8))) unsigned short ushort8_t;
typedef __attribute__((ext_vector_type(4))) float f32x4;

#define AS1q const __attribute__((address_space(1)))
#define AS3q __attribute__((address_space(3)))

__device__ inline unsigned short f2bf(float f) {
    unsigned u = __builtin_bit_cast(unsigned, f);
    u += 0x7fffu + ((u >> 16) & 1u);   // RNE (no NaN inputs here)
    return (unsigned short)(u >> 16);
}
__device__ inline float bf2f(unsigned short u) {
    return __builtin_bit_cast(float, ((unsigned)u) << 16);
}

// ---------------- fused prep: qkv + W converts ------------------------------
__global__ __launch_bounds__(256) void prep(
    const float* __restrict__ query, const float* __restrict__ key,
    const float* __restrict__ value,
    const float* __restrict__ Wq, const float* __restrict__ Wk,
    const float* __restrict__ Wv, const float* __restrict__ Wo,
    unsigned short* __restrict__ qc, unsigned short* __restrict__ kc,
    unsigned short* __restrict__ vc,
    unsigned short* __restrict__ wqb, unsigned short* __restrict__ wkb,
    unsigned short* __restrict__ wvb, unsigned short* __restrict__ wob)
{
    int bid = blockIdx.x;
    const float* x;
    unsigned short* y;
    size_t i;
    if (bid < 12288) {
        int z = bid >> 12;                 // 0..2
        x = (z == 0) ? query : (z == 1) ? key : value;
        y = (z == 0) ? qc : (z == 1) ? kc : vc;
        i = ((size_t)(bid & 4095) * 256 + threadIdx.x) * 4;
    } else {
        int r = bid - 12288;
        int z = r >> 8;                    // 0..3
        x = (z == 0) ? Wq : (z == 1) ? Wk : (z == 2) ? Wv : Wo;
        y = (z == 0) ? wqb : (z == 1) ? wkb : (z == 2) ? wvb : wob;
        i = ((size_t)(r & 255) * 256 + threadIdx.x) * 4;
    }
    float4 v = *(const float4*)&x[i];
    *(ushort4*)&y[i] = make_ushort4(f2bf(v.x), f2bf(v.y), f2bf(v.z), f2bf(v.w));
}

// ---------------- bf16 GEMM, m97-style: global_load_lds + XOR-swizzled LDS --
template<int TN>
__global__ __launch_bounds__(256) void gemm_bf16(
    const unsigned short* __restrict__ A0, const unsigned short* __restrict__ A1,
    const unsigned short* __restrict__ A2,
    const unsigned short* __restrict__ W0, const unsigned short* __restrict__ W1,
    const unsigned short* __restrict__ W2,
    const float* __restrict__ bi0, const float* __restrict__ bi1, const float* __restrict__ bi2,
    unsigned short* __restrict__ C0, unsigned short* __restrict__ C1,
    unsigned short* __restrict__ C2,
    float* __restrict__ Cf, int a_bhsd)
{
    constexpr int NFR = TN / 32;           // B frags per wave (4 or 2)
    __shared__ unsigned short As[128 * 64];
    __shared__ unsigned short Bs[TN * 64];
    const int z = blockIdx.z;
    const unsigned short* A = (z == 0) ? A0 : (z == 1) ? A1 : A2;
    const unsigned short* W = (z == 0) ? W0 : (z == 1) ? W1 : W2;
    const float* bias        = (z == 0) ? bi0 : (z == 1) ? bi1 : bi2;
    unsigned short* C        = (z == 0) ? C0 : (z == 1) ? C1 : C2;

    const int t    = threadIdx.x;
    const int lane = t & 63;
    const int w    = t >> 6;
    const int wm   = w >> 1, wn = w & 1;
    const int m0   = blockIdx.x * 128;
    const int n0   = blockIdx.y * TN;

    const int lr    = lane >> 3;           // row within 8-row stage chunk
    const int cglob = (lane & 7) ^ lr;     // swizzled global source chunk

    f32x4 acc[4][NFR] = {};

    for (int kk = 0; kk < D_; kk += 64) {
        #pragma unroll
        for (int i = 0; i < 4; ++i) {
            int rowl = w * 32 + i * 8;         // wave-uniform LDS row base
            int m = m0 + rowl + lr;
            const unsigned short* ga;
            if (a_bhsd) {
                int b = m >> 11, s = m & (S_ - 1), h = kk >> 6;
                ga = A + ((((size_t)b * H_ + h) * S_ + s) << 6) + cglob * 8;
            } else {
                ga = A + (size_t)m * D_ + kk + cglob * 8;
            }
            __builtin_amdgcn_global_load_lds((AS1q unsigned*)ga,
                (AS3q unsigned*)(As + rowl * 64), 16, 0, 0);
        }
        #pragma unroll
        for (int i = 0; i < TN / 32; ++i) {
            int rowl = w * (TN / 4) + i * 8;
            const unsigned short* gb =
                W + (size_t)(n0 + rowl + lr) * D_ + kk + cglob * 8;
            __builtin_amdgcn_global_load_lds((AS1q unsigned*)gb,
                (AS3q unsigned*)(Bs + rowl * 64), 16, 0, 0);
        }
        __syncthreads();

        #pragma unroll
        for (int ks = 0; ks < 64; ks += 32) {
            const int c0 = ks >> 3;            // 0 or 4
            bf16x8 af[4], bfr[NFR];
            #pragma unroll
            for (int mi = 0; mi < 4; ++mi) {
                int row = wm * 64 + mi * 16 + (lane & 15);
                int cp  = (c0 + (lane >> 4)) ^ (lane & 7);
                af[mi] = *(const bf16x8*)&As[row * 64 + cp * 8];
            }
            #pragma unroll
            for (int nj = 0; nj < NFR; ++nj) {
                int row = wn * (TN / 2) + nj * 16 + (lane & 15);
                int cp  = (c0 + (lane >> 4)) ^ (lane & 7);
                bfr[nj] = *(const bf16x8*)&Bs[row * 64 + cp * 8];
            }
            #pragma unroll
            for (int mi = 0; mi < 4; ++mi)
                #pragma unroll
                for (int nj = 0; nj < NFR; ++nj)
                    acc[mi][nj] = __builtin_amdgcn_mfma_f32_16x16x32_bf16(af[mi], bfr[nj], acc[mi][nj], 0, 0, 0);
        }
        __syncthreads();
    }

    // epilogue: C/D layout col = lane&15, row = (lane>>4)*4 + reg
    #pragma unroll
    for (int mi = 0; mi < 4; ++mi) {
        #pragma unroll
        for (int nj = 0; nj < NFR; ++nj) {
            #pragma unroll
            for (int r = 0; r < 4; ++r) {
                int m = m0 + wm * 64 + mi * 16 + (lane >> 4) * 4 + r;
                int n = n0 + wn * (TN / 2) + nj * 16 + (lane & 15);
                float val = acc[mi][nj][r] + bias[n];
                if (Cf) {
                    Cf[(size_t)m * D_ + n] = val;
                } else {
                    int b = m >> 11, s = m & (S_ - 1);
                    int h = n >> 6,  d = n & 63;
                    C[((((size_t)b * H_ + h) * S_ + s) << 6) + d] = f2bf(val);
                }
            }
        }
    }
}

// ---------------- rank-1 score-term tables via MFMA -------------------------
// qrk[node][r2] = (q[node].rel_k[h][r2])/24 ; rqk[node][r2] = (rel_q[h][r2].k[node])/24
__global__ __launch_bounds__(256) void rel_dots(
    const unsigned short* __restrict__ q, const unsigned short* __restrict__ k_,
    const float* __restrict__ rel_q, const float* __restrict__ rel_k,
    float* __restrict__ qrk, float* __restrict__ rqk)
{
    const int t    = threadIdx.x;
    const int lane = t & 63;
    const int w    = t >> 6;
    const int n0   = blockIdx.x * 128 + w * 32;   // wave's 32-node base (never crosses bh)
    const int h    = (n0 >> 11) & 7;
    const int r2   = lane & 15;
    const int ch   = lane >> 4;                   // 0..3: 8-elem k-chunk

    // B fragments for both k-halves, both tables (f32 -> bf16 in-register)
    bf16x8 bk2[2], bq2[2];
    #pragma unroll
    for (int ks = 0; ks < 2; ++ks) {
        const float* pk = rel_k + (((h << 4) + r2) << 6) + ks * 32 + ch * 8;
        const float* pq = rel_q + (((h << 4) + r2) << 6) + ks * 32 + ch * 8;
        f32x4 k0 = *(const f32x4*)pk, k1 = *(const f32x4*)(pk + 4);
        f32x4 q0 = *(const f32x4*)pq, q1 = *(const f32x4*)(pq + 4);
        bf16x8 bk, bq;
        #pragma unroll
        for (int i = 0; i < 4; ++i) {
            bk[i]     = (short)f2bf(k0[i]);
            bk[4 + i] = (short)f2bf(k1[i]);
            bq[i]     = (short)f2bf(q0[i]);
            bq[4 + i] = (short)f2bf(q1[i]);
        }
        bk2[ks] = bk; bq2[ks] = bq;
    }

    f32x4 aq[2] = {{0.f,0.f,0.f,0.f},{0.f,0.f,0.f,0.f}};
    f32x4 ak[2] = {{0.f,0.f,0.f,0.f},{0.f,0.f,0.f,0.f}};
    #pragma unroll
    for (int mi = 0; mi < 2; ++mi) {
        int m = n0 + mi * 16 + r2;               // A-frag row = lane&15
        #pragma unroll
        for (int ks = 0; ks < 2; ++ks) {
            bf16x8 aqf = *(const bf16x8*)&q [((size_t)m << 6) + ks * 32 + ch * 8];
            bf16x8 akf = *(const bf16x8*)&k_[((size_t)m << 6) + ks * 32 + ch * 8];
            aq[mi] = __builtin_amdgcn_mfma_f32_16x16x32_bf16(aqf, bk2[ks], aq[mi], 0, 0, 0);
            ak[mi] = __builtin_amdgcn_mfma_f32_16x16x32_bf16(akf, bq2[ks], ak[mi], 0, 0, 0);
        }
    }
    #pragma unroll
    for (int mi = 0; mi < 2; ++mi) {
        #pragma unroll
        for (int r = 0; r < 4; ++r) {
            int m = n0 + mi * 16 + (ch << 2) + r;
            qrk[((size_t)m << 4) + r2] = aq[mi][r] * SCALE_;
            rqk[((size_t)m << 4) + r2] = ak[mi][r] * SCALE_;
        }
    }
}

// ---------------- fused ELL-build + score+softmax+aggregate -----------------
// One block per (bh, 128-dst window). Scan: coalesced int2 reads (r2>=1) and
// per-edge rank-1 term tb gathered HERE (latency hidden in scan flow) into
// ell_tb. Gather: R3-proven structure — group-per-dst (no epilogue reduce),
// explicit 1-deep staged-register pipeline, NO launch_bounds min-wave pin
// (R4's 64-VGPR cap + 2-deep stages caused 500 MB of scratch traffic).
__global__ __launch_bounds__(1024) void attn_fused(
    const unsigned short* __restrict__ q, const unsigned short* __restrict__ k_,
    const unsigned short* __restrict__ v_,
    const float* __restrict__ qrk, const float* __restrict__ rqk,
    const float* __restrict__ rel_v,
    const int* __restrict__ start_nodes, const int* __restrict__ end_nodes,
    unsigned short* __restrict__ attn)
{
    __shared__ unsigned short ell[128 * ELLSTRIDE];   // 18 KB
    __shared__ float ell_tb[128 * ELLSTRIDE];         // 36.9 KB
    __shared__ int cnt[128];
    const int bi  = blockIdx.x;          // 512 blocks
    const int xcd = bi & 7;
    const int loc = bi >> 3;             // 0..63
    const int bh  = xcd * 4 + (loc >> 4);
    const int dlo = (loc & 15) << 7;     // 128-dst window base
    const int t   = threadIdx.x;

    if (t < 128) cnt[t] = 0;
    __syncthreads();

    const size_t node_base = ((size_t)bh << 11);
    const float* qrk_bh = qrk + (node_base << 4);
    const float* rqk_bh = rqk + (node_base << 4);

    // ---- scan phase: coalesced int2 read of this bh's edge lists ----
    const int base_idx = bh * (R_ * S_);
    for (int f = S_ + t * 2; f < EPB; f += 2048) {   // 15 iterations, r2>=1
        int r2 = f >> 11;
        int s  = f & (S_ - 1);                        // even
        int idx = base_idx + ((r2 & 7) << 11) + s;
        int2 sn2 = *(const int2*)&start_nodes[idx];
        int2 en2 = *(const int2*)&end_nodes[idx];
        #pragma unroll
        for (int u = 0; u < 2; ++u) {
            int sn = u ? sn2.y : sn2.x;
            if (sn == -1) continue;                   // padded edge
            int en = u ? en2.y : en2.x;
            int dst = (r2 < R_) ? en : sn;
            unsigned rel = (unsigned)(dst - dlo);
            if (rel < 128u) {
                int ki = (r2 < R_) ? sn : en;
                // rank-1 terms gathered here (latency hidden by scan flow)
                float tb = qrk_bh[((size_t)dst << 4) + r2]
                         + rqk_bh[((size_t)ki  << 4) + r2];
                int pos = atomicAdd(&cnt[rel], 1);
                if (pos < ELLCAP) {
                    ell[rel * ELLSTRIDE + pos]    = (unsigned short)((r2 << 11) | ki);
                    ell_tb[rel * ELLSTRIDE + pos] = tb;
                }
            }
        }
    }
    __syncthreads();

    // ---- gather phase: group g of wave w owns dst dlo + w*8 + g ----
    const int w    = t >> 6;
    const int lane = t & 63;
    const int g    = lane >> 3;          // group (dst) within wave
    const int sub  = lane & 7;           // dk chunk (8 elems)
    const int dl   = w * 8 + g;          // 0..127
    const int dst  = dlo + dl;
    const int h    = bh & 7;
    const float* rvh = rel_v + ((size_t)(h << 4) << 6);   // [16][64] f32

    ushort8_t q8 = *(const ushort8_t*)&q[((node_base + dst) << 6) + sub * 8];
    float qv[8];
    #pragma unroll
    for (int i = 0; i < 8; ++i) qv[i] = bf2f(q8[i]);

    int n = cnt[dl];
    if (n > ELLCAP) n = ELLCAP;
    int nmax = n;
    nmax = max(nmax, __shfl_xor(nmax, 8));
    nmax = max(nmax, __shfl_xor(nmax, 16));
    nmax = max(nmax, __shfl_xor(nmax, 32));

    const unsigned short* er  = &ell[dl * ELLSTRIDE];
    const float*          etb = &ell_tb[dl * ELLSTRIDE];

    float den = 0.f;
    float o[8] = {};

    // pipeline prologue: edge 0 (er row padded to 72 -> j+1 reads safe;
    // garbage ki stays in-bounds, invalid slots get tb=-1e30 -> exp()==0)
    int d0 = er[0];
    int ki = d0 & (S_ - 1);
    int r2 = (d0 >> 11) & 15;
    ushort8_t k8 = *(const ushort8_t*)&k_[((node_base + ki) << 6) + sub * 8];
    ushort8_t v8 = *(const ushort8_t*)&v_[((node_base + ki) << 6) + sub * 8];
    float tb = (0 < n) ? etb[0] : -1e30f;

    for (int j = 0; j < nmax; ++j) {
        // prefetch edge j+1
        int dn = er[j + 1];
        int kin = dn & (S_ - 1);
        int r2n = (dn >> 11) & 15;
        ushort8_t k8n = *(const ushort8_t*)&k_[((node_base + kin) << 6) + sub * 8];
        ushort8_t v8n = *(const ushort8_t*)&v_[((node_base + kin) << 6) + sub * 8];
        float tbn = ((j + 1) < n) ? etb[j + 1] : -1e30f;

        // compute edge j
        float p = 0.f;
        #pragma unroll
        for (int i = 0; i < 8; ++i)
            p = fmaf(bf2f(k8[i]), qv[i], p);
        p += __shfl_xor(p, 1);
        p += __shfl_xor(p, 2);
        p += __shfl_xor(p, 4);
        float sf = __expf(fmaf(p, SCALE_, tb));
        const float* rvp = rvh + (r2 << 6) + sub * 8;
        f32x4 rv0 = *(const f32x4*)rvp;
        f32x4 rv1 = *(const f32x4*)(rvp + 4);
        den += sf;
        #pragma unroll
        for (int i = 0; i < 4; ++i)
            o[i] = fmaf(sf, bf2f(v8[i]) + rv0[i], o[i]);
        #pragma unroll
        for (int i = 0; i < 4; ++i)
            o[4 + i] = fmaf(sf, bf2f(v8[4 + i]) + rv1[i], o[4 + i]);

        // rotate pipeline
        k8 = k8n; v8 = v8n; tb = tbn; r2 = r2n;
    }

    // epilogue: den/o complete per-lane (sf uniform in-group), no reduce
    float inv = (den > 0.f) ? 1.0f / den : 0.f;
    ushort8_t r;
    #pragma unroll
    for (int i = 0; i < 8; ++i) r[i] = f2bf(o[i] * inv);
    *(ushort8_t*)&attn[((node_base + dst) << 6) + sub * 8] = r;
}

extern "C" void kernel_launch(void* const* d_in, const int* in_sizes, int n_in,
                              void* d_out, int out_size, void* d_ws, size_t ws_size,
                              hipStream_t stream) {
    const float* query = (const float*)d_in[0];
    const float* key   = (const float*)d_in[1];
    const float* value = (const float*)d_in[2];
    const int* start_nodes = (const int*)d_in[3];
    const int* end_nodes   = (const int*)d_in[4];
    const float* rel_q = (const float*)d_in[5];
    const float* rel_k = (const float*)d_in[6];
    const float* rel_v = (const float*)d_in[7];
    const float* Wq = (const float*)d_in[8];
    const float* bq = (const float*)d_in[9];
    const float* Wk = (const float*)d_in[10];
    const float* bk = (const float*)d_in[11];
    const float* Wv = (const float*)d_in[12];
    const float* bv = (const float*)d_in[13];
    const float* Wo = (const float*)d_in[14];
    const float* bo = (const float*)d_in[15];
    float* out = (float*)d_out;

    const size_t NQ = (size_t)B_ * H_ * S_ * DK_;   // 4,194,304
    const size_t NW = (size_t)D_ * D_;              // 262,144
    unsigned short* p = (unsigned short*)d_ws;
    unsigned short* qc = p;            p += NQ;
    unsigned short* kc = p;            p += NQ;
    unsigned short* vc = p;            p += NQ;
    unsigned short* q  = p;            p += NQ;
    unsigned short* k  = p;            p += NQ;
    unsigned short* v  = p;            p += NQ;
    unsigned short* attn = p;          p += NQ;
    unsigned short* wqb = p;           p += NW;
    unsigned short* wkb = p;           p += NW;
    unsigned short* wvb = p;           p += NW;
    unsigned short* wob = p;           p += NW;
    // score-term tables alias qc (dead after GEMM1): 2 x 1M f32 = 8 MB = |qc|
    float* qrk = (float*)qc;
    float* rqk = qrk + ((size_t)1 << 20);

    // 1) fused converts (one dispatch)
    prep<<<13312, 256, 0, stream>>>(query, key, value, Wq, Wk, Wv, Wo,
                                    qc, kc, vc, wqb, wkb, wvb, wob);

    // 2) fused QKV projection (128x128 tiles, 768 blocks)
    dim3 ggrid(B_ * S_ / 128, D_ / 128, 3);
    gemm_bf16<128><<<ggrid, 256, 0, stream>>>(qc, kc, vc, wqb, wkb, wvb, bq, bk, bv,
                                              q, k, v, nullptr, 0);

    // 3) rank-1 score-term tables via MFMA (q.rel_k, rel_q.k), prescaled by 1/24
    rel_dots<<<512, 256, 0, stream>>>(q, k, rel_q, rel_k, qrk, rqk);

    // 4) fused ELL-build + attention (no global ELL)
    attn_fused<<<512, 1024, 0, stream>>>(q, k, v, qrk, rqk, rel_v,
                                         start_nodes, end_nodes, attn);

    // 5) output projection (128x64 tiles -> 512 blocks = 2/CU, fp32 out)
    dim3 ogrid(B_ * S_ / 128, D_ / 64, 1);
    gemm_bf16<64><<<ogrid, 256, 0, stream>>>(attn, attn, attn, wob, wob, wob, bo, bo, bo,
                                             nullptr, nullptr, nullptr, out, 1);
}

// Round 6
// 209.567 us; speedup vs baseline: 1.5504x; 1.0497x over previous
//
#include <hip/hip_runtime.h>
#include <math.h>

// Problem constants (fixed by reference): B=4, S=2048, D=512, H=8, R=8, dk=64
#define B_ 4
#define S_ 2048
#define D_ 512
#define H_ 8
#define R_ 8
#define DK_ 64
#define NEDGE (B_*H_*2*R_*S_)   // 1,048,576
#define EPB   (2*R_*S_)         // 32768 edges per (b,h)
#define ELLCAP 64               // max in-degree slots; Poisson(15) tail ~2e-8
#define ELLSTRIDE 72            // padded row stride (bank-spread + prefetch slack)
#define SCALE_ (1.0f/24.0f)     // 1/(3*sqrt(dk))

typedef __attribute__((ext_vector_type(8))) short bf16x8;
typedef __attribute__((ext_vector_type(8))) unsigned short ushort8_t;
typedef __attribute__((ext_vector_type(4))) float f32x4;

#define AS1q const __attribute__((address_space(1)))
#define AS3q __attribute__((address_space(3)))

__device__ inline unsigned short f2bf(float f) {
    unsigned u = __builtin_bit_cast(unsigned, f);
    u += 0x7fffu + ((u >> 16) & 1u);   // RNE (no NaN inputs here)
    return (unsigned short)(u >> 16);
}
__device__ inline float bf2f(unsigned short u) {
    return __builtin_bit_cast(float, ((unsigned)u) << 16);
}
// HW packed f32->bf16 (RNE), per T12 recipe (no builtin on gfx950)
__device__ inline unsigned cvtpk(float lo, float hi) {
    unsigned r;
    asm("v_cvt_pk_bf16_f32 %0,%1,%2" : "=v"(r) : "v"(lo), "v"(hi));
    return r;
}

// ---------------- prep: W converts only (qkv conversion fused into GEMM1) ---
__global__ __launch_bounds__(256) void prepW(
    const float* __restrict__ Wq, const float* __restrict__ Wk,
    const float* __restrict__ Wv, const float* __restrict__ Wo,
    unsigned short* __restrict__ wqb, unsigned short* __restrict__ wkb,
    unsigned short* __restrict__ wvb, unsigned short* __restrict__ wob)
{
    int bid = blockIdx.x;              // 1024 blocks, 256 per matrix
    int z = bid >> 8;
    const float* x = (z == 0) ? Wq : (z == 1) ? Wk : (z == 2) ? Wv : Wo;
    unsigned short* y = (z == 0) ? wqb : (z == 1) ? wkb : (z == 2) ? wvb : wob;
    size_t i = ((size_t)(bid & 255) * 256 + threadIdx.x) * 4;
    float4 v = *(const float4*)&x[i];
    *(ushort4*)&y[i] = make_ushort4(f2bf(v.x), f2bf(v.y), f2bf(v.z), f2bf(v.w));
}

// ---------------- bf16 GEMM, m97-style ---------------------------------------
// AF32=1: A is fp32 row-major; A-tile reg-staged (f32 loads -> cvt_pk bf16 ->
// ds_write_b128) into the SAME XOR-swizzled layout the gload_lds path makes:
// LDS[r][c] = global[r][c ^ (r&7)]  (read path: cp = g ^ (lane&7), r%8==lane&7).
// AF32=0: A is bf16 via global_load_lds (optionally bhsd-layout, for GEMM2).
// B (weights) always via global_load_lds.
template<int TN, int AF32>
__global__ __launch_bounds__(256) void gemm_bf16(
    const void* A0, const void* A1, const void* A2,
    const unsigned short* __restrict__ W0, const unsigned short* __restrict__ W1,
    const unsigned short* __restrict__ W2,
    const float* __restrict__ bi0, const float* __restrict__ bi1, const float* __restrict__ bi2,
    unsigned short* __restrict__ C0, unsigned short* __restrict__ C1,
    unsigned short* __restrict__ C2,
    float* __restrict__ Cf, int a_bhsd)
{
    constexpr int NFR = TN / 32;           // B frags per wave (4 or 2)
    __shared__ unsigned short As[128 * 64];
    __shared__ unsigned short Bs[TN * 64];
    const int z = blockIdx.z;
    const void* Av = (z == 0) ? A0 : (z == 1) ? A1 : A2;
    const unsigned short* W = (z == 0) ? W0 : (z == 1) ? W1 : W2;
    const float* bias        = (z == 0) ? bi0 : (z == 1) ? bi1 : bi2;
    unsigned short* C        = (z == 0) ? C0 : (z == 1) ? C1 : C2;

    const int t    = threadIdx.x;
    const int lane = t & 63;
    const int w    = t >> 6;
    const int wm   = w >> 1, wn = w & 1;
    const int m0   = blockIdx.x * 128;
    const int n0   = blockIdx.y * TN;

    const int lr    = lane >> 3;           // row within 8-row stage chunk
    const int cglob = (lane & 7) ^ lr;     // swizzled global source chunk

    f32x4 acc[4][NFR] = {};

    for (int kk = 0; kk < D_; kk += 64) {
        if constexpr (AF32) {
            const float* Af = (const float*)Av;
            #pragma unroll
            for (int i = 0; i < 4; ++i) {
                int rowl = w * 32 + i * 8;
                int m = m0 + rowl + lr;
                const float* ga = Af + (size_t)m * D_ + kk + cglob * 8;
                f32x4 x0 = *(const f32x4*)ga;
                f32x4 x1 = *(const f32x4*)(ga + 4);
                unsigned pk0 = cvtpk(x0[0], x0[1]);
                unsigned pk1 = cvtpk(x0[2], x0[3]);
                unsigned pk2 = cvtpk(x1[0], x1[1]);
                unsigned pk3 = cvtpk(x1[2], x1[3]);
                // dest: row rowl+lr, chunk lane&7 (matches gload_lds layout)
                *(uint4*)&As[(rowl + lr) * 64 + (lane & 7) * 8] =
                    make_uint4(pk0, pk1, pk2, pk3);
            }
        } else {
            const unsigned short* A = (const unsigned short*)Av;
            #pragma unroll
            for (int i = 0; i < 4; ++i) {
                int rowl = w * 32 + i * 8;         // wave-uniform LDS row base
                int m = m0 + rowl + lr;
                const unsigned short* ga;
                if (a_bhsd) {
                    int b = m >> 11, s = m & (S_ - 1), h = kk >> 6;
                    ga = A + ((((size_t)b * H_ + h) * S_ + s) << 6) + cglob * 8;
                } else {
                    ga = A + (size_t)m * D_ + kk + cglob * 8;
                }
                __builtin_amdgcn_global_load_lds((AS1q unsigned*)ga,
                    (AS3q unsigned*)(As + rowl * 64), 16, 0, 0);
            }
        }
        #pragma unroll
        for (int i = 0; i < TN / 32; ++i) {
            int rowl = w * (TN / 4) + i * 8;
            const unsigned short* gb =
                W + (size_t)(n0 + rowl + lr) * D_ + kk + cglob * 8;
            __builtin_amdgcn_global_load_lds((AS1q unsigned*)gb,
                (AS3q unsigned*)(Bs + rowl * 64), 16, 0, 0);
        }
        __syncthreads();

        #pragma unroll
        for (int ks = 0; ks < 64; ks += 32) {
            const int c0 = ks >> 3;            // 0 or 4
            bf16x8 af[4], bfr[NFR];
            #pragma unroll
            for (int mi = 0; mi < 4; ++mi) {
                int row = wm * 64 + mi * 16 + (lane & 15);
                int cp  = (c0 + (lane >> 4)) ^ (lane & 7);
                af[mi] = *(const bf16x8*)&As[row * 64 + cp * 8];
            }
            #pragma unroll
            for (int nj = 0; nj < NFR; ++nj) {
                int row = wn * (TN / 2) + nj * 16 + (lane & 15);
                int cp  = (c0 + (lane >> 4)) ^ (lane & 7);
                bfr[nj] = *(const bf16x8*)&Bs[row * 64 + cp * 8];
            }
            #pragma unroll
            for (int mi = 0; mi < 4; ++mi)
                #pragma unroll
                for (int nj = 0; nj < NFR; ++nj)
                    acc[mi][nj] = __builtin_amdgcn_mfma_f32_16x16x32_bf16(af[mi], bfr[nj], acc[mi][nj], 0, 0, 0);
        }
        __syncthreads();
    }

    // epilogue: C/D layout col = lane&15, row = (lane>>4)*4 + reg
    #pragma unroll
    for (int mi = 0; mi < 4; ++mi) {
        #pragma unroll
        for (int nj = 0; nj < NFR; ++nj) {
            #pragma unroll
            for (int r = 0; r < 4; ++r) {
                int m = m0 + wm * 64 + mi * 16 + (lane >> 4) * 4 + r;
                int n = n0 + wn * (TN / 2) + nj * 16 + (lane & 15);
                float val = acc[mi][nj][r] + bias[n];
                if (Cf) {
                    Cf[(size_t)m * D_ + n] = val;
                } else {
                    int b = m >> 11, s = m & (S_ - 1);
                    int h = n >> 6,  d = n & 63;
                    C[((((size_t)b * H_ + h) * S_ + s) << 6) + d] = f2bf(val);
                }
            }
        }
    }
}

// ---------------- rank-1 score-term tables via MFMA -------------------------
// qrk[node][r2] = (q[node].rel_k[h][r2])/24 ; rqk[node][r2] = (rel_q[h][r2].k[node])/24
__global__ __launch_bounds__(256) void rel_dots(
    const unsigned short* __restrict__ q, const unsigned short* __restrict__ k_,
    const float* __restrict__ rel_q, const float* __restrict__ rel_k,
    float* __restrict__ qrk, float* __restrict__ rqk)
{
    const int t    = threadIdx.x;
    const int lane = t & 63;
    const int w    = t >> 6;
    const int n0   = blockIdx.x * 128 + w * 32;   // wave's 32-node base (never crosses bh)
    const int h    = (n0 >> 11) & 7;
    const int r2   = lane & 15;
    const int ch   = lane >> 4;                   // 0..3: 8-elem k-chunk

    // B fragments for both k-halves, both tables (f32 -> bf16 in-register)
    bf16x8 bk2[2], bq2[2];
    #pragma unroll
    for (int ks = 0; ks < 2; ++ks) {
        const float* pk = rel_k + (((h << 4) + r2) << 6) + ks * 32 + ch * 8;
        const float* pq = rel_q + (((h << 4) + r2) << 6) + ks * 32 + ch * 8;
        f32x4 k0 = *(const f32x4*)pk, k1 = *(const f32x4*)(pk + 4);
        f32x4 q0 = *(const f32x4*)pq, q1 = *(const f32x4*)(pq + 4);
        bf16x8 bk, bq;
        #pragma unroll
        for (int i = 0; i < 4; ++i) {
            bk[i]     = (short)f2bf(k0[i]);
            bk[4 + i] = (short)f2bf(k1[i]);
            bq[i]     = (short)f2bf(q0[i]);
            bq[4 + i] = (short)f2bf(q1[i]);
        }
        bk2[ks] = bk; bq2[ks] = bq;
    }

    f32x4 aq[2] = {{0.f,0.f,0.f,0.f},{0.f,0.f,0.f,0.f}};
    f32x4 ak[2] = {{0.f,0.f,0.f,0.f},{0.f,0.f,0.f,0.f}};
    #pragma unroll
    for (int mi = 0; mi < 2; ++mi) {
        int m = n0 + mi * 16 + r2;               // A-frag row = lane&15
        #pragma unroll
        for (int ks = 0; ks < 2; ++ks) {
            bf16x8 aqf = *(const bf16x8*)&q [((size_t)m << 6) + ks * 32 + ch * 8];
            bf16x8 akf = *(const bf16x8*)&k_[((size_t)m << 6) + ks * 32 + ch * 8];
            aq[mi] = __builtin_amdgcn_mfma_f32_16x16x32_bf16(aqf, bk2[ks], aq[mi], 0, 0, 0);
            ak[mi] = __builtin_amdgcn_mfma_f32_16x16x32_bf16(akf, bq2[ks], ak[mi], 0, 0, 0);
        }
    }
    #pragma unroll
    for (int mi = 0; mi < 2; ++mi) {
        #pragma unroll
        for (int r = 0; r < 4; ++r) {
            int m = n0 + mi * 16 + (ch << 2) + r;
            qrk[((size_t)m << 4) + r2] = aq[mi][r] * SCALE_;
            rqk[((size_t)m << 4) + r2] = ak[mi][r] * SCALE_;
        }
    }
}

// ---------------- fused ELL-build + score+softmax+aggregate -----------------
// R3-proven version (51.3 us): scan with int2 reads (r2>=1); gather with
// group-per-dst (no epilogue reduce), 1-deep staged-register pipeline,
// in-loop rqk gather (adequately hidden by prefetch + 8-wave TLP; moving it
// to scan (R5) cost occupancy and regressed).
__global__ __launch_bounds__(1024) void attn_fused(
    const unsigned short* __restrict__ q, const unsigned short* __restrict__ k_,
    const unsigned short* __restrict__ v_,
    const float* __restrict__ qrk, const float* __restrict__ rqk,
    const float* __restrict__ rel_v,
    const int* __restrict__ start_nodes, const int* __restrict__ end_nodes,
    unsigned short* __restrict__ attn)
{
    __shared__ unsigned short ell[128 * ELLSTRIDE];   // 18 KB
    __shared__ int cnt[128];
    const int bi  = blockIdx.x;          // 512 blocks
    const int xcd = bi & 7;
    const int loc = bi >> 3;             // 0..63
    const int bh  = xcd * 4 + (loc >> 4);
    const int dlo = (loc & 15) << 7;     // 128-dst window base
    const int t   = threadIdx.x;

    if (t < 128) cnt[t] = 0;
    __syncthreads();

    // ---- scan phase: coalesced int2 read of this bh's edge lists ----
    const int base_idx = bh * (R_ * S_);
    for (int f = S_ + t * 2; f < EPB; f += 2048) {   // 15 iterations, r2>=1
        int r2 = f >> 11;
        int s  = f & (S_ - 1);                        // even
        int idx = base_idx + ((r2 & 7) << 11) + s;
        int2 sn2 = *(const int2*)&start_nodes[idx];
        int2 en2 = *(const int2*)&end_nodes[idx];
        #pragma unroll
        for (int u = 0; u < 2; ++u) {
            int sn = u ? sn2.y : sn2.x;
            if (sn == -1) continue;                   // padded edge
            int en = u ? en2.y : en2.x;
            int dst = (r2 < R_) ? en : sn;
            unsigned rel = (unsigned)(dst - dlo);
            if (rel < 128u) {
                int ki = (r2 < R_) ? sn : en;
                int pos = atomicAdd(&cnt[rel], 1);
                if (pos < ELLCAP)
                    ell[rel * ELLSTRIDE + pos] = (unsigned short)((r2 << 11) | ki);
            }
        }
    }
    __syncthreads();

    // ---- gather phase: group g of wave w owns dst dlo + w*8 + g ----
    const int w    = t >> 6;
    const int lane = t & 63;
    const int g    = lane >> 3;          // group (dst) within wave
    const int sub  = lane & 7;           // dk chunk (8 elems)
    const int dl   = w * 8 + g;          // 0..127
    const int dst  = dlo + dl;
    const int h    = bh & 7;
    const size_t node_base = ((size_t)bh << 11);
    const float* qrk_bh = qrk + (node_base << 4);
    const float* rqk_bh = rqk + (node_base << 4);
    const float* rvh    = rel_v + ((size_t)(h << 4) << 6);   // [16][64] f32

    ushort8_t q8 = *(const ushort8_t*)&q[((node_base + dst) << 6) + sub * 8];
    float qv[8];
    #pragma unroll
    for (int i = 0; i < 8; ++i) qv[i] = bf2f(q8[i]);
    const float* qrow = qrk_bh + ((size_t)dst << 4);

    int n = cnt[dl];
    if (n > ELLCAP) n = ELLCAP;
    int nmax = n;
    nmax = max(nmax, __shfl_xor(nmax, 8));
    nmax = max(nmax, __shfl_xor(nmax, 16));
    nmax = max(nmax, __shfl_xor(nmax, 32));

    const unsigned short* er = &ell[dl * ELLSTRIDE];

    float den = 0.f;
    float o[8] = {};

    // pipeline prologue: edge 0
    int d0 = er[0];
    int ki = (0 < n) ? (d0 & (S_ - 1)) : 0;
    int r2 = (0 < n) ? ((d0 >> 11) & 15) : 0;
    ushort8_t k8 = *(const ushort8_t*)&k_[((node_base + ki) << 6) + sub * 8];
    ushort8_t v8 = *(const ushort8_t*)&v_[((node_base + ki) << 6) + sub * 8];
    float tb = qrow[r2] + rqk_bh[((size_t)ki << 4) + r2];

    for (int j = 0; j < nmax; ++j) {
        // prefetch edge j+1 (indices clamped -> safe loads; row padded to 72)
        bool vn = (j + 1) < n;
        int dn = er[j + 1];
        int kin = vn ? (dn & (S_ - 1)) : 0;
        int r2n = vn ? ((dn >> 11) & 15) : 0;
        ushort8_t k8n = *(const ushort8_t*)&k_[((node_base + kin) << 6) + sub * 8];
        ushort8_t v8n = *(const ushort8_t*)&v_[((node_base + kin) << 6) + sub * 8];
        float tbn = qrow[r2n] + rqk_bh[((size_t)kin << 4) + r2n];

        // compute edge j
        bool valid = j < n;
        float p = 0.f;
        #pragma unroll
        for (int i = 0; i < 8; ++i)
            p = fmaf(bf2f(k8[i]), qv[i], p);
        p += __shfl_xor(p, 1);
        p += __shfl_xor(p, 2);
        p += __shfl_xor(p, 4);
        float sf = valid ? __expf(fmaf(p, SCALE_, tb)) : 0.f;
        const float* rvp = rvh + (r2 << 6) + sub * 8;
        f32x4 rv0 = *(const f32x4*)rvp;
        f32x4 rv1 = *(const f32x4*)(rvp + 4);
        den += sf;
        #pragma unroll
        for (int i = 0; i < 4; ++i)
            o[i] = fmaf(sf, bf2f(v8[i]) + rv0[i], o[i]);
        #pragma unroll
        for (int i = 0; i < 4; ++i)
            o[4 + i] = fmaf(sf, bf2f(v8[4 + i]) + rv1[i], o[4 + i]);

        // rotate pipeline
        k8 = k8n; v8 = v8n; tb = tbn; r2 = r2n;
    }

    // epilogue: den/o complete per-lane (sf uniform in-group), no reduce
    float inv = (den > 0.f) ? 1.0f / den : 0.f;
    ushort8_t r;
    #pragma unroll
    for (int i = 0; i < 8; ++i) r[i] = f2bf(o[i] * inv);
    *(ushort8_t*)&attn[((node_base + dst) << 6) + sub * 8] = r;
}

extern "C" void kernel_launch(void* const* d_in, const int* in_sizes, int n_in,
                              void* d_out, int out_size, void* d_ws, size_t ws_size,
                              hipStream_t stream) {
    const float* query = (const float*)d_in[0];
    const float* key   = (const float*)d_in[1];
    const float* value = (const float*)d_in[2];
    const int* start_nodes = (const int*)d_in[3];
    const int* end_nodes   = (const int*)d_in[4];
    const float* rel_q = (const float*)d_in[5];
    const float* rel_k = (const float*)d_in[6];
    const float* rel_v = (const float*)d_in[7];
    const float* Wq = (const float*)d_in[8];
    const float* bq = (const float*)d_in[9];
    const float* Wk = (const float*)d_in[10];
    const float* bk = (const float*)d_in[11];
    const float* Wv = (const float*)d_in[12];
    const float* bv = (const float*)d_in[13];
    const float* Wo = (const float*)d_in[14];
    const float* bo = (const float*)d_in[15];
    float* out = (float*)d_out;

    const size_t NQ = (size_t)B_ * H_ * S_ * DK_;   // 4,194,304
    const size_t NW = (size_t)D_ * D_;              // 262,144
    unsigned short* p = (unsigned short*)d_ws;
    unsigned short* q    = p;          p += NQ;
    unsigned short* k    = p;          p += NQ;
    unsigned short* v    = p;          p += NQ;
    unsigned short* attn = p;          p += NQ;
    unsigned short* wqb  = p;          p += NW;
    unsigned short* wkb  = p;          p += NW;
    unsigned short* wvb  = p;          p += NW;
    unsigned short* wob  = p;          p += NW;
    float* qrk = (float*)p;            // 2 x 1M f32 = 8 MB
    float* rqk = qrk + ((size_t)1 << 20);

    // 1) W converts only (qkv conversion fused into GEMM1's A-staging)
    prepW<<<1024, 256, 0, stream>>>(Wq, Wk, Wv, Wo, wqb, wkb, wvb, wob);

    // 2) fused QKV projection, A read as f32 + converted in-kernel
    dim3 ggrid(B_ * S_ / 128, D_ / 128, 3);
    gemm_bf16<128, 1><<<ggrid, 256, 0, stream>>>(
        query, key, value, wqb, wkb, wvb, bq, bk, bv, q, k, v, nullptr, 0);

    // 3) rank-1 score-term tables via MFMA (q.rel_k, rel_q.k), prescaled by 1/24
    rel_dots<<<512, 256, 0, stream>>>(q, k, rel_q, rel_k, qrk, rqk);

    // 4) fused ELL-build + attention (R3-proven gather)
    attn_fused<<<512, 1024, 0, stream>>>(q, k, v, qrk, rqk, rel_v,
                                         start_nodes, end_nodes, attn);

    // 5) output projection (128x64 tiles -> 512 blocks, fp32 out)
    dim3 ogrid(B_ * S_ / 128, D_ / 64, 1);
    gemm_bf16<64, 0><<<ogrid, 256, 0, stream>>>(
        attn, attn, attn, wob, wob, wob, bo, bo, bo,
        nullptr, nullptr, nullptr, out, 1);
}

// Round 7
// 207.407 us; speedup vs baseline: 1.5665x; 1.0104x over previous
//
#include <hip/hip_runtime.h>
#include <math.h>

// Problem constants (fixed by reference): B=4, S=2048, D=512, H=8, R=8, dk=64
#define B_ 4
#define S_ 2048
#define D_ 512
#define H_ 8
#define R_ 8
#define DK_ 64
#define NEDGE (B_*H_*2*R_*S_)   // 1,048,576
#define EPB   (2*R_*S_)         // 32768 edges per (b,h)
#define ELLCAP 64               // max in-degree slots; Poisson(15) tail ~2e-8
#define ELLSTRIDE 72            // padded row stride (bank-spread + prefetch slack)
#define SCALE_ (1.0f/24.0f)     // 1/(3*sqrt(dk))

typedef __attribute__((ext_vector_type(8))) short bf16x8;
typedef __attribute__((ext_vector_type(8))) unsigned short ushort8_t;
typedef __attribute__((ext_vector_type(4))) float f32x4;

#define AS1q const __attribute__((address_space(1)))
#define AS3q __attribute__((address_space(3)))

__device__ inline unsigned short f2bf(float f) {
    unsigned u = __builtin_bit_cast(unsigned, f);
    u += 0x7fffu + ((u >> 16) & 1u);   // RNE (no NaN inputs here)
    return (unsigned short)(u >> 16);
}
__device__ inline float bf2f(unsigned short u) {
    return __builtin_bit_cast(float, ((unsigned)u) << 16);
}
// HW packed f32->bf16 (RNE), per T12 recipe (no builtin on gfx950)
__device__ inline unsigned cvtpk(float lo, float hi) {
    unsigned r;
    asm("v_cvt_pk_bf16_f32 %0,%1,%2" : "=v"(r) : "v"(lo), "v"(hi));
    return r;
}

// ---------------- prep: W converts only (qkv conversion fused into GEMM1) ---
__global__ __launch_bounds__(256) void prepW(
    const float* __restrict__ Wq, const float* __restrict__ Wk,
    const float* __restrict__ Wv, const float* __restrict__ Wo,
    unsigned short* __restrict__ wqb, unsigned short* __restrict__ wkb,
    unsigned short* __restrict__ wvb, unsigned short* __restrict__ wob)
{
    int bid = blockIdx.x;              // 1024 blocks, 256 per matrix
    int z = bid >> 8;
    const float* x = (z == 0) ? Wq : (z == 1) ? Wk : (z == 2) ? Wv : Wo;
    unsigned short* y = (z == 0) ? wqb : (z == 1) ? wkb : (z == 2) ? wvb : wob;
    size_t i = ((size_t)(bid & 255) * 256 + threadIdx.x) * 4;
    float4 v = *(const float4*)&x[i];
    *(ushort4*)&y[i] = make_ushort4(f2bf(v.x), f2bf(v.y), f2bf(v.z), f2bf(v.w));
}

// ---------------- bf16 GEMM, m97-style ---------------------------------------
// AF32=1: A is fp32 row-major, conversion fused. R7: A-stage software-pipelined
// (T14 issue-early/write-late): regs for step kk are loaded AFTER barrier1 of
// step kk-64, so the f32 load latency hides under compute and drains at the
// trailing barrier. Per-iter cvt_pk + ds_write lands in the SAME XOR-swizzled
// layout the gload_lds path makes: LDS[r][c] = global[r][c ^ (r&7)]
// (read path: cp = g ^ (lane&7), row&7 == lane&7).
// AF32=0: A is bf16 via global_load_lds (optionally bhsd-layout, for GEMM2).
// B (weights) always via global_load_lds.
template<int TN, int AF32>
__global__ __launch_bounds__(256) void gemm_bf16(
    const void* A0, const void* A1, const void* A2,
    const unsigned short* __restrict__ W0, const unsigned short* __restrict__ W1,
    const unsigned short* __restrict__ W2,
    const float* __restrict__ bi0, const float* __restrict__ bi1, const float* __restrict__ bi2,
    unsigned short* __restrict__ C0, unsigned short* __restrict__ C1,
    unsigned short* __restrict__ C2,
    float* __restrict__ Cf, int a_bhsd)
{
    constexpr int NFR = TN / 32;           // B frags per wave (4 or 2)
    __shared__ unsigned short As[128 * 64];
    __shared__ unsigned short Bs[TN * 64];
    const int z = blockIdx.z;
    const void* Av = (z == 0) ? A0 : (z == 1) ? A1 : A2;
    const unsigned short* W = (z == 0) ? W0 : (z == 1) ? W1 : W2;
    const float* bias        = (z == 0) ? bi0 : (z == 1) ? bi1 : bi2;
    unsigned short* C        = (z == 0) ? C0 : (z == 1) ? C1 : C2;

    const int t    = threadIdx.x;
    const int lane = t & 63;
    const int w    = t >> 6;
    const int wm   = w >> 1, wn = w & 1;
    const int m0   = blockIdx.x * 128;
    const int n0   = blockIdx.y * TN;

    const int lr    = lane >> 3;           // row within 8-row stage chunk
    const int cglob = (lane & 7) ^ lr;     // swizzled global source chunk

    f32x4 acc[4][NFR] = {};
    f32x4 xa[4][2];                        // AF32 staged A regs (32 VGPR)

    if constexpr (AF32) {
        const float* Af = (const float*)Av;
        #pragma unroll
        for (int i = 0; i < 4; ++i) {
            int m = m0 + w * 32 + i * 8 + lr;
            const float* ga = Af + (size_t)m * D_ + cglob * 8;
            xa[i][0] = *(const f32x4*)ga;
            xa[i][1] = *(const f32x4*)(ga + 4);
        }
    }

    for (int kk = 0; kk < D_; kk += 64) {
        if constexpr (AF32) {
            // write staged regs (loaded last iter, drained by trailing barrier)
            #pragma unroll
            for (int i = 0; i < 4; ++i) {
                int rowl = w * 32 + i * 8;
                unsigned pk0 = cvtpk(xa[i][0][0], xa[i][0][1]);
                unsigned pk1 = cvtpk(xa[i][0][2], xa[i][0][3]);
                unsigned pk2 = cvtpk(xa[i][1][0], xa[i][1][1]);
                unsigned pk3 = cvtpk(xa[i][1][2], xa[i][1][3]);
                *(uint4*)&As[(rowl + lr) * 64 + (lane & 7) * 8] =
                    make_uint4(pk0, pk1, pk2, pk3);
            }
        } else {
            const unsigned short* A = (const unsigned short*)Av;
            #pragma unroll
            for (int i = 0; i < 4; ++i) {
                int rowl = w * 32 + i * 8;         // wave-uniform LDS row base
                int m = m0 + rowl + lr;
                const unsigned short* ga;
                if (a_bhsd) {
                    int b = m >> 11, s = m & (S_ - 1), h = kk >> 6;
                    ga = A + ((((size_t)b * H_ + h) * S_ + s) << 6) + cglob * 8;
                } else {
                    ga = A + (size_t)m * D_ + kk + cglob * 8;
                }
                __builtin_amdgcn_global_load_lds((AS1q unsigned*)ga,
                    (AS3q unsigned*)(As + rowl * 64), 16, 0, 0);
            }
        }
        #pragma unroll
        for (int i = 0; i < TN / 32; ++i) {
            int rowl = w * (TN / 4) + i * 8;
            const unsigned short* gb =
                W + (size_t)(n0 + rowl + lr) * D_ + kk + cglob * 8;
            __builtin_amdgcn_global_load_lds((AS1q unsigned*)gb,
                (AS3q unsigned*)(Bs + rowl * 64), 16, 0, 0);
        }
        __syncthreads();

        if constexpr (AF32) {
            // issue NEXT K-step's A loads; latency hides under compute below,
            // drained by the trailing barrier (not serially mid-stage)
            if (kk + 64 < D_) {
                const float* Af = (const float*)Av;
                #pragma unroll
                for (int i = 0; i < 4; ++i) {
                    int m = m0 + w * 32 + i * 8 + lr;
                    const float* ga = Af + (size_t)m * D_ + (kk + 64) + cglob * 8;
                    xa[i][0] = *(const f32x4*)ga;
                    xa[i][1] = *(const f32x4*)(ga + 4);
                }
            }
        }

        #pragma unroll
        for (int ks = 0; ks < 64; ks += 32) {
            const int c0 = ks >> 3;            // 0 or 4
            bf16x8 af[4], bfr[NFR];
            #pragma unroll
            for (int mi = 0; mi < 4; ++mi) {
                int row = wm * 64 + mi * 16 + (lane & 15);
                int cp  = (c0 + (lane >> 4)) ^ (lane & 7);
                af[mi] = *(const bf16x8*)&As[row * 64 + cp * 8];
            }
            #pragma unroll
            for (int nj = 0; nj < NFR; ++nj) {
                int row = wn * (TN / 2) + nj * 16 + (lane & 15);
                int cp  = (c0 + (lane >> 4)) ^ (lane & 7);
                bfr[nj] = *(const bf16x8*)&Bs[row * 64 + cp * 8];
            }
            #pragma unroll
            for (int mi = 0; mi < 4; ++mi)
                #pragma unroll
                for (int nj = 0; nj < NFR; ++nj)
                    acc[mi][nj] = __builtin_amdgcn_mfma_f32_16x16x32_bf16(af[mi], bfr[nj], acc[mi][nj], 0, 0, 0);
        }
        __syncthreads();
    }

    // epilogue: C/D layout col = lane&15, row = (lane>>4)*4 + reg
    #pragma unroll
    for (int mi = 0; mi < 4; ++mi) {
        #pragma unroll
        for (int nj = 0; nj < NFR; ++nj) {
            #pragma unroll
            for (int r = 0; r < 4; ++r) {
                int m = m0 + wm * 64 + mi * 16 + (lane >> 4) * 4 + r;
                int n = n0 + wn * (TN / 2) + nj * 16 + (lane & 15);
                float val = acc[mi][nj][r] + bias[n];
                if (Cf) {
                    Cf[(size_t)m * D_ + n] = val;
                } else {
                    int b = m >> 11, s = m & (S_ - 1);
                    int h = n >> 6,  d = n & 63;
                    C[((((size_t)b * H_ + h) * S_ + s) << 6) + d] = f2bf(val);
                }
            }
        }
    }
}

// ---------------- rank-1 score-term tables via MFMA -------------------------
// qrk[node][r2] = (q[node].rel_k[h][r2])/24 ; rqk[node][r2] = (rel_q[h][r2].k[node])/24
__global__ __launch_bounds__(256) void rel_dots(
    const unsigned short* __restrict__ q, const unsigned short* __restrict__ k_,
    const float* __restrict__ rel_q, const float* __restrict__ rel_k,
    float* __restrict__ qrk, float* __restrict__ rqk)
{
    const int t    = threadIdx.x;
    const int lane = t & 63;
    const int w    = t >> 6;
    const int n0   = blockIdx.x * 128 + w * 32;   // wave's 32-node base (never crosses bh)
    const int h    = (n0 >> 11) & 7;
    const int r2   = lane & 15;
    const int ch   = lane >> 4;                   // 0..3: 8-elem k-chunk

    // B fragments for both k-halves, both tables (f32 -> bf16 in-register)
    bf16x8 bk2[2], bq2[2];
    #pragma unroll
    for (int ks = 0; ks < 2; ++ks) {
        const float* pk = rel_k + (((h << 4) + r2) << 6) + ks * 32 + ch * 8;
        const float* pq = rel_q + (((h << 4) + r2) << 6) + ks * 32 + ch * 8;
        f32x4 k0 = *(const f32x4*)pk, k1 = *(const f32x4*)(pk + 4);
        f32x4 q0 = *(const f32x4*)pq, q1 = *(const f32x4*)(pq + 4);
        bf16x8 bk, bq;
        #pragma unroll
        for (int i = 0; i < 4; ++i) {
            bk[i]     = (short)f2bf(k0[i]);
            bk[4 + i] = (short)f2bf(k1[i]);
            bq[i]     = (short)f2bf(q0[i]);
            bq[4 + i] = (short)f2bf(q1[i]);
        }
        bk2[ks] = bk; bq2[ks] = bq;
    }

    f32x4 aq[2] = {{0.f,0.f,0.f,0.f},{0.f,0.f,0.f,0.f}};
    f32x4 ak[2] = {{0.f,0.f,0.f,0.f},{0.f,0.f,0.f,0.f}};
    #pragma unroll
    for (int mi = 0; mi < 2; ++mi) {
        int m = n0 + mi * 16 + r2;               // A-frag row = lane&15
        #pragma unroll
        for (int ks = 0; ks < 2; ++ks) {
            bf16x8 aqf = *(const bf16x8*)&q [((size_t)m << 6) + ks * 32 + ch * 8];
            bf16x8 akf = *(const bf16x8*)&k_[((size_t)m << 6) + ks * 32 + ch * 8];
            aq[mi] = __builtin_amdgcn_mfma_f32_16x16x32_bf16(aqf, bk2[ks], aq[mi], 0, 0, 0);
            ak[mi] = __builtin_amdgcn_mfma_f32_16x16x32_bf16(akf, bq2[ks], ak[mi], 0, 0, 0);
        }
    }
    #pragma unroll
    for (int mi = 0; mi < 2; ++mi) {
        #pragma unroll
        for (int r = 0; r < 4; ++r) {
            int m = n0 + mi * 16 + (ch << 2) + r;
            qrk[((size_t)m << 4) + r2] = aq[mi][r] * SCALE_;
            rqk[((size_t)m << 4) + r2] = ak[mi][r] * SCALE_;
        }
    }
}

// ---------------- fused ELL-build + score+softmax+aggregate -----------------
// R3-proven version: scan with int2 reads (r2>=1); gather with group-per-dst
// (no epilogue reduce), 1-deep staged-register pipeline, in-loop rqk gather
// (hidden by prefetch + 8-wave TLP; R5's tb-in-scan cost occupancy, regressed).
__global__ __launch_bounds__(1024) void attn_fused(
    const unsigned short* __restrict__ q, const unsigned short* __restrict__ k_,
    const unsigned short* __restrict__ v_,
    const float* __restrict__ qrk, const float* __restrict__ rqk,
    const float* __restrict__ rel_v,
    const int* __restrict__ start_nodes, const int* __restrict__ end_nodes,
    unsigned short* __restrict__ attn)
{
    __shared__ unsigned short ell[128 * ELLSTRIDE];   // 18 KB
    __shared__ int cnt[128];
    const int bi  = blockIdx.x;          // 512 blocks
    const int xcd = bi & 7;
    const int loc = bi >> 3;             // 0..63
    const int bh  = xcd * 4 + (loc >> 4);
    const int dlo = (loc & 15) << 7;     // 128-dst window base
    const int t   = threadIdx.x;

    if (t < 128) cnt[t] = 0;
    __syncthreads();

    // ---- scan phase: coalesced int2 read of this bh's edge lists ----
    const int base_idx = bh * (R_ * S_);
    for (int f = S_ + t * 2; f < EPB; f += 2048) {   // 15 iterations, r2>=1
        int r2 = f >> 11;
        int s  = f & (S_ - 1);                        // even
        int idx = base_idx + ((r2 & 7) << 11) + s;
        int2 sn2 = *(const int2*)&start_nodes[idx];
        int2 en2 = *(const int2*)&end_nodes[idx];
        #pragma unroll
        for (int u = 0; u < 2; ++u) {
            int sn = u ? sn2.y : sn2.x;
            if (sn == -1) continue;                   // padded edge
            int en = u ? en2.y : en2.x;
            int dst = (r2 < R_) ? en : sn;
            unsigned rel = (unsigned)(dst - dlo);
            if (rel < 128u) {
                int ki = (r2 < R_) ? sn : en;
                int pos = atomicAdd(&cnt[rel], 1);
                if (pos < ELLCAP)
                    ell[rel * ELLSTRIDE + pos] = (unsigned short)((r2 << 11) | ki);
            }
        }
    }
    __syncthreads();

    // ---- gather phase: group g of wave w owns dst dlo + w*8 + g ----
    const int w    = t >> 6;
    const int lane = t & 63;
    const int g    = lane >> 3;          // group (dst) within wave
    const int sub  = lane & 7;           // dk chunk (8 elems)
    const int dl   = w * 8 + g;          // 0..127
    const int dst  = dlo + dl;
    const int h    = bh & 7;
    const size_t node_base = ((size_t)bh << 11);
    const float* qrk_bh = qrk + (node_base << 4);
    const float* rqk_bh = rqk + (node_base << 4);
    const float* rvh    = rel_v + ((size_t)(h << 4) << 6);   // [16][64] f32

    ushort8_t q8 = *(const ushort8_t*)&q[((node_base + dst) << 6) + sub * 8];
    float qv[8];
    #pragma unroll
    for (int i = 0; i < 8; ++i) qv[i] = bf2f(q8[i]);
    const float* qrow = qrk_bh + ((size_t)dst << 4);

    int n = cnt[dl];
    if (n > ELLCAP) n = ELLCAP;
    int nmax = n;
    nmax = max(nmax, __shfl_xor(nmax, 8));
    nmax = max(nmax, __shfl_xor(nmax, 16));
    nmax = max(nmax, __shfl_xor(nmax, 32));

    const unsigned short* er = &ell[dl * ELLSTRIDE];

    float den = 0.f;
    float o[8] = {};

    // pipeline prologue: edge 0
    int d0 = er[0];
    int ki = (0 < n) ? (d0 & (S_ - 1)) : 0;
    int r2 = (0 < n) ? ((d0 >> 11) & 15) : 0;
    ushort8_t k8 = *(const ushort8_t*)&k_[((node_base + ki) << 6) + sub * 8];
    ushort8_t v8 = *(const ushort8_t*)&v_[((node_base + ki) << 6) + sub * 8];
    float tb = qrow[r2] + rqk_bh[((size_t)ki << 4) + r2];

    for (int j = 0; j < nmax; ++j) {
        // prefetch edge j+1 (indices clamped -> safe loads; row padded to 72)
        bool vn = (j + 1) < n;
        int dn = er[j + 1];
        int kin = vn ? (dn & (S_ - 1)) : 0;
        int r2n = vn ? ((dn >> 11) & 15) : 0;
        ushort8_t k8n = *(const ushort8_t*)&k_[((node_base + kin) << 6) + sub * 8];
        ushort8_t v8n = *(const ushort8_t*)&v_[((node_base + kin) << 6) + sub * 8];
        float tbn = qrow[r2n] + rqk_bh[((size_t)kin << 4) + r2n];

        // compute edge j
        bool valid = j < n;
        float p = 0.f;
        #pragma unroll
        for (int i = 0; i < 8; ++i)
            p = fmaf(bf2f(k8[i]), qv[i], p);
        p += __shfl_xor(p, 1);
        p += __shfl_xor(p, 2);
        p += __shfl_xor(p, 4);
        float sf = valid ? __expf(fmaf(p, SCALE_, tb)) : 0.f;
        const float* rvp = rvh + (r2 << 6) + sub * 8;
        f32x4 rv0 = *(const f32x4*)rvp;
        f32x4 rv1 = *(const f32x4*)(rvp + 4);
        den += sf;
        #pragma unroll
        for (int i = 0; i < 4; ++i)
            o[i] = fmaf(sf, bf2f(v8[i]) + rv0[i], o[i]);
        #pragma unroll
        for (int i = 0; i < 4; ++i)
            o[4 + i] = fmaf(sf, bf2f(v8[4 + i]) + rv1[i], o[4 + i]);

        // rotate pipeline
        k8 = k8n; v8 = v8n; tb = tbn; r2 = r2n;
    }

    // epilogue: den/o complete per-lane (sf uniform in-group), no reduce
    float inv = (den > 0.f) ? 1.0f / den : 0.f;
    ushort8_t r;
    #pragma unroll
    for (int i = 0; i < 8; ++i) r[i] = f2bf(o[i] * inv);
    *(ushort8_t*)&attn[((node_base + dst) << 6) + sub * 8] = r;
}

extern "C" void kernel_launch(void* const* d_in, const int* in_sizes, int n_in,
                              void* d_out, int out_size, void* d_ws, size_t ws_size,
                              hipStream_t stream) {
    const float* query = (const float*)d_in[0];
    const float* key   = (const float*)d_in[1];
    const float* value = (const float*)d_in[2];
    const int* start_nodes = (const int*)d_in[3];
    const int* end_nodes   = (const int*)d_in[4];
    const float* rel_q = (const float*)d_in[5];
    const float* rel_k = (const float*)d_in[6];
    const float* rel_v = (const float*)d_in[7];
    const float* Wq = (const float*)d_in[8];
    const float* bq = (const float*)d_in[9];
    const float* Wk = (const float*)d_in[10];
    const float* bk = (const float*)d_in[11];
    const float* Wv = (const float*)d_in[12];
    const float* bv = (const float*)d_in[13];
    const float* Wo = (const float*)d_in[14];
    const float* bo = (const float*)d_in[15];
    float* out = (float*)d_out;

    const size_t NQ = (size_t)B_ * H_ * S_ * DK_;   // 4,194,304
    const size_t NW = (size_t)D_ * D_;              // 262,144
    unsigned short* p = (unsigned short*)d_ws;
    unsigned short* q    = p;          p += NQ;
    unsigned short* k    = p;          p += NQ;
    unsigned short* v    = p;          p += NQ;
    unsigned short* attn = p;          p += NQ;
    unsigned short* wqb  = p;          p += NW;
    unsigned short* wkb  = p;          p += NW;
    unsigned short* wvb  = p;          p += NW;
    unsigned short* wob  = p;          p += NW;
    float* qrk = (float*)p;            // 2 x 1M f32 = 8 MB
    float* rqk = qrk + ((size_t)1 << 20);

    // 1) W converts only (qkv conversion fused into GEMM1's A-staging)
    prepW<<<1024, 256, 0, stream>>>(Wq, Wk, Wv, Wo, wqb, wkb, wvb, wob);

    // 2) fused QKV projection, A read as f32 + converted in-kernel (pipelined)
    dim3 ggrid(B_ * S_ / 128, D_ / 128, 3);
    gemm_bf16<128, 1><<<ggrid, 256, 0, stream>>>(
        query, key, value, wqb, wkb, wvb, bq, bk, bv, q, k, v, nullptr, 0);

    // 3) rank-1 score-term tables via MFMA (q.rel_k, rel_q.k), prescaled by 1/24
    rel_dots<<<512, 256, 0, stream>>>(q, k, rel_q, rel_k, qrk, rqk);

    // 4) fused ELL-build + attention (R3-proven gather)
    attn_fused<<<512, 1024, 0, stream>>>(q, k, v, qrk, rqk, rel_v,
                                         start_nodes, end_nodes, attn);

    // 5) output projection (128x64 tiles -> 512 blocks, fp32 out)
    dim3 ogrid(B_ * S_ / 128, D_ / 64, 1);
    gemm_bf16<64, 0><<<ogrid, 256, 0, stream>>>(
        attn, attn, attn, wob, wob, wob, bo, bo, bo,
        nullptr, nullptr, nullptr, out, 1);
}

// Round 8
// 201.904 us; speedup vs baseline: 1.6092x; 1.0273x over previous
//
#include <hip/hip_runtime.h>
#include <math.h>

// Problem constants (fixed by reference): B=4, S=2048, D=512, H=8, R=8, dk=64
#define B_ 4
#define S_ 2048
#define D_ 512
#define H_ 8
#define R_ 8
#define DK_ 64
#define NEDGE (B_*H_*2*R_*S_)   // 1,048,576
#define EPB   (2*R_*S_)         // 32768 edge slots per (b,h)
#define ELLCAP 64               // max in-degree slots; Poisson(15) tail ~2e-8
#define ELLSTRIDE 72            // padded row stride (bank-spread + depth-2 prefetch slack)
#define SCALE_ (1.0f/24.0f)     // 1/(3*sqrt(dk))

typedef __attribute__((ext_vector_type(8))) short bf16x8;
typedef __attribute__((ext_vector_type(8))) unsigned short ushort8_t;
typedef __attribute__((ext_vector_type(4))) float f32x4;

#define AS1q const __attribute__((address_space(1)))
#define AS3q __attribute__((address_space(3)))

__device__ inline unsigned short f2bf(float f) {
    unsigned u = __builtin_bit_cast(unsigned, f);
    u += 0x7fffu + ((u >> 16) & 1u);   // RNE (no NaN inputs here)
    return (unsigned short)(u >> 16);
}
__device__ inline float bf2f(unsigned short u) {
    return __builtin_bit_cast(float, ((unsigned)u) << 16);
}
// HW packed f32->bf16 (RNE), per T12 recipe (no builtin on gfx950)
__device__ inline unsigned cvtpk(float lo, float hi) {
    unsigned r;
    asm("v_cvt_pk_bf16_f32 %0,%1,%2" : "=v"(r) : "v"(lo), "v"(hi));
    return r;
}

// ---------------- prep: W converts only (qkv conversion fused into GEMM1) ---
__global__ __launch_bounds__(256) void prepW(
    const float* __restrict__ Wq, const float* __restrict__ Wk,
    const float* __restrict__ Wv, const float* __restrict__ Wo,
    unsigned short* __restrict__ wqb, unsigned short* __restrict__ wkb,
    unsigned short* __restrict__ wvb, unsigned short* __restrict__ wob)
{
    int bid = blockIdx.x;              // 1024 blocks, 256 per matrix
    int z = bid >> 8;
    const float* x = (z == 0) ? Wq : (z == 1) ? Wk : (z == 2) ? Wv : Wo;
    unsigned short* y = (z == 0) ? wqb : (z == 1) ? wkb : (z == 2) ? wvb : wob;
    size_t i = ((size_t)(bid & 255) * 256 + threadIdx.x) * 4;
    float4 v = *(const float4*)&x[i];
    *(ushort4*)&y[i] = make_ushort4(f2bf(v.x), f2bf(v.y), f2bf(v.z), f2bf(v.w));
}

// ---------------- bf16 GEMM, m97-style ---------------------------------------
// AF32=1: A fp32 row-major, conversion fused; A-stage software-pipelined (T14):
// regs for step kk loaded AFTER barrier1 of step kk-64 (latency hides under
// compute, drains at trailing barrier). cvt_pk + ds_write into the SAME
// XOR-swizzled layout the gload_lds path makes: LDS[r][c] = global[r][c^(r&7)].
// AF32=0: A bf16 via global_load_lds (optionally bhsd, for GEMM2).
// B (weights) always bf16 via global_load_lds.
template<int TN, int AF32>
__global__ __launch_bounds__(256) void gemm_bf16(
    const void* A0, const void* A1, const void* A2,
    const unsigned short* __restrict__ W0, const unsigned short* __restrict__ W1,
    const unsigned short* __restrict__ W2,
    const float* __restrict__ bi0, const float* __restrict__ bi1, const float* __restrict__ bi2,
    unsigned short* __restrict__ C0, unsigned short* __restrict__ C1,
    unsigned short* __restrict__ C2,
    float* __restrict__ Cf, int a_bhsd)
{
    constexpr int NFR = TN / 32;           // B frags per wave (4 or 2)
    __shared__ unsigned short As[128 * 64];
    __shared__ unsigned short Bs[TN * 64];
    const int z = blockIdx.z;
    const void* Av = (z == 0) ? A0 : (z == 1) ? A1 : A2;
    const unsigned short* W = (z == 0) ? W0 : (z == 1) ? W1 : W2;
    const float* bias        = (z == 0) ? bi0 : (z == 1) ? bi1 : bi2;
    unsigned short* C        = (z == 0) ? C0 : (z == 1) ? C1 : C2;

    const int t    = threadIdx.x;
    const int lane = t & 63;
    const int w    = t >> 6;
    const int wm   = w >> 1, wn = w & 1;
    const int m0   = blockIdx.x * 128;
    const int n0   = blockIdx.y * TN;

    const int lr    = lane >> 3;           // row within 8-row stage chunk
    const int cglob = (lane & 7) ^ lr;     // swizzled global source chunk

    f32x4 acc[4][NFR] = {};
    f32x4 xa[4][2];                        // AF32 staged A regs (32 VGPR)

    if constexpr (AF32) {
        const float* Af = (const float*)Av;
        #pragma unroll
        for (int i = 0; i < 4; ++i) {
            int m = m0 + w * 32 + i * 8 + lr;
            const float* ga = Af + (size_t)m * D_ + cglob * 8;
            xa[i][0] = *(const f32x4*)ga;
            xa[i][1] = *(const f32x4*)(ga + 4);
        }
    }

    for (int kk = 0; kk < D_; kk += 64) {
        if constexpr (AF32) {
            // write staged regs (loaded last iter, drained by trailing barrier)
            #pragma unroll
            for (int i = 0; i < 4; ++i) {
                int rowl = w * 32 + i * 8;
                unsigned pk0 = cvtpk(xa[i][0][0], xa[i][0][1]);
                unsigned pk1 = cvtpk(xa[i][0][2], xa[i][0][3]);
                unsigned pk2 = cvtpk(xa[i][1][0], xa[i][1][1]);
                unsigned pk3 = cvtpk(xa[i][1][2], xa[i][1][3]);
                *(uint4*)&As[(rowl + lr) * 64 + (lane & 7) * 8] =
                    make_uint4(pk0, pk1, pk2, pk3);
            }
        } else {
            const unsigned short* A = (const unsigned short*)Av;
            #pragma unroll
            for (int i = 0; i < 4; ++i) {
                int rowl = w * 32 + i * 8;         // wave-uniform LDS row base
                int m = m0 + rowl + lr;
                const unsigned short* ga;
                if (a_bhsd) {
                    int b = m >> 11, s = m & (S_ - 1), h = kk >> 6;
                    ga = A + ((((size_t)b * H_ + h) * S_ + s) << 6) + cglob * 8;
                } else {
                    ga = A + (size_t)m * D_ + kk + cglob * 8;
                }
                __builtin_amdgcn_global_load_lds((AS1q unsigned*)ga,
                    (AS3q unsigned*)(As + rowl * 64), 16, 0, 0);
            }
        }
        #pragma unroll
        for (int i = 0; i < TN / 32; ++i) {
            int rowl = w * (TN / 4) + i * 8;
            const unsigned short* gb =
                W + (size_t)(n0 + rowl + lr) * D_ + kk + cglob * 8;
            __builtin_amdgcn_global_load_lds((AS1q unsigned*)gb,
                (AS3q unsigned*)(Bs + rowl * 64), 16, 0, 0);
        }
        __syncthreads();

        if constexpr (AF32) {
            // issue NEXT K-step's A loads; latency hides under compute below
            if (kk + 64 < D_) {
                const float* Af = (const float*)Av;
                #pragma unroll
                for (int i = 0; i < 4; ++i) {
                    int m = m0 + w * 32 + i * 8 + lr;
                    const float* ga = Af + (size_t)m * D_ + (kk + 64) + cglob * 8;
                    xa[i][0] = *(const f32x4*)ga;
                    xa[i][1] = *(const f32x4*)(ga + 4);
                }
            }
        }

        #pragma unroll
        for (int ks = 0; ks < 64; ks += 32) {
            const int c0 = ks >> 3;            // 0 or 4
            bf16x8 af[4], bfr[NFR];
            #pragma unroll
            for (int mi = 0; mi < 4; ++mi) {
                int row = wm * 64 + mi * 16 + (lane & 15);
                int cp  = (c0 + (lane >> 4)) ^ (lane & 7);
                af[mi] = *(const bf16x8*)&As[row * 64 + cp * 8];
            }
            #pragma unroll
            for (int nj = 0; nj < NFR; ++nj) {
                int row = wn * (TN / 2) + nj * 16 + (lane & 15);
                int cp  = (c0 + (lane >> 4)) ^ (lane & 7);
                bfr[nj] = *(const bf16x8*)&Bs[row * 64 + cp * 8];
            }
            #pragma unroll
            for (int mi = 0; mi < 4; ++mi)
                #pragma unroll
                for (int nj = 0; nj < NFR; ++nj)
                    acc[mi][nj] = __builtin_amdgcn_mfma_f32_16x16x32_bf16(af[mi], bfr[nj], acc[mi][nj], 0, 0, 0);
        }
        __syncthreads();
    }

    // epilogue: C/D layout col = lane&15, row = (lane>>4)*4 + reg
    #pragma unroll
    for (int mi = 0; mi < 4; ++mi) {
        #pragma unroll
        for (int nj = 0; nj < NFR; ++nj) {
            #pragma unroll
            for (int r = 0; r < 4; ++r) {
                int m = m0 + wm * 64 + mi * 16 + (lane >> 4) * 4 + r;
                int n = n0 + wn * (TN / 2) + nj * 16 + (lane & 15);
                float val = acc[mi][nj][r] + bias[n];
                if (Cf) {
                    Cf[(size_t)m * D_ + n] = val;
                } else {
                    int b = m >> 11, s = m & (S_ - 1);
                    int h = n >> 6,  d = n & 63;
                    C[((((size_t)b * H_ + h) * S_ + s) << 6) + d] = f2bf(val);
                }
            }
        }
    }
}

// ---------------- rank-1 score-term tables via MFMA -------------------------
// qrk[node][r2] = (q[node].rel_k[h][r2])/24 ; rqk[node][r2] = (rel_q[h][r2].k[node])/24
__global__ __launch_bounds__(256) void rel_dots(
    const unsigned short* __restrict__ q, const unsigned short* __restrict__ k_,
    const float* __restrict__ rel_q, const float* __restrict__ rel_k,
    float* __restrict__ qrk, float* __restrict__ rqk)
{
    const int t    = threadIdx.x;
    const int lane = t & 63;
    const int w    = t >> 6;
    const int n0   = blockIdx.x * 128 + w * 32;   // wave's 32-node base (never crosses bh)
    const int h    = (n0 >> 11) & 7;
    const int r2   = lane & 15;
    const int ch   = lane >> 4;                   // 0..3: 8-elem k-chunk

    // B fragments for both k-halves, both tables (f32 -> bf16 in-register)
    bf16x8 bk2[2], bq2[2];
    #pragma unroll
    for (int ks = 0; ks < 2; ++ks) {
        const float* pk = rel_k + (((h << 4) + r2) << 6) + ks * 32 + ch * 8;
        const float* pq = rel_q + (((h << 4) + r2) << 6) + ks * 32 + ch * 8;
        f32x4 k0 = *(const f32x4*)pk, k1 = *(const f32x4*)(pk + 4);
        f32x4 q0 = *(const f32x4*)pq, q1 = *(const f32x4*)(pq + 4);
        bf16x8 bk, bq;
        #pragma unroll
        for (int i = 0; i < 4; ++i) {
            bk[i]     = (short)f2bf(k0[i]);
            bk[4 + i] = (short)f2bf(k1[i]);
            bq[i]     = (short)f2bf(q0[i]);
            bq[4 + i] = (short)f2bf(q1[i]);
        }
        bk2[ks] = bk; bq2[ks] = bq;
    }

    f32x4 aq[2] = {{0.f,0.f,0.f,0.f},{0.f,0.f,0.f,0.f}};
    f32x4 ak[2] = {{0.f,0.f,0.f,0.f},{0.f,0.f,0.f,0.f}};
    #pragma unroll
    for (int mi = 0; mi < 2; ++mi) {
        int m = n0 + mi * 16 + r2;               // A-frag row = lane&15
        #pragma unroll
        for (int ks = 0; ks < 2; ++ks) {
            bf16x8 aqf = *(const bf16x8*)&q [((size_t)m << 6) + ks * 32 + ch * 8];
            bf16x8 akf = *(const bf16x8*)&k_[((size_t)m << 6) + ks * 32 + ch * 8];
            aq[mi] = __builtin_amdgcn_mfma_f32_16x16x32_bf16(aqf, bk2[ks], aq[mi], 0, 0, 0);
            ak[mi] = __builtin_amdgcn_mfma_f32_16x16x32_bf16(akf, bq2[ks], ak[mi], 0, 0, 0);
        }
    }
    #pragma unroll
    for (int mi = 0; mi < 2; ++mi) {
        #pragma unroll
        for (int r = 0; r < 4; ++r) {
            int m = n0 + mi * 16 + (ch << 2) + r;
            qrk[((size_t)m << 4) + r2] = aq[mi][r] * SCALE_;
            rqk[((size_t)m << 4) + r2] = ak[mi][r] * SCALE_;
        }
    }
}

// ---------------- fused ELL-build + score+softmax+aggregate -----------------
// R8 scan: iterate r=0..7 (8 iters, HALF of R7's 15) — one int2 pair read per
// underlying edge, claiming BOTH directions (r2=r: dst=en,ki=sn for r>=1;
// r2=r+8: dst=sn,ki=en). Same claim count, half the VMEM/loop overhead.
// R8 gather: depth-2 INDEX prefetch — d1=er[j+1] is in-register from the
// previous iteration, so k8n/v8n/tbn L2 loads issue at the TOP of iter j with
// no LDS dependency (R7's er->k8 chain was ~170cy exposed); er[j+2] fetched
// in parallel. Costs ~2 VGPR; no staged k/v duplication, no launch_bounds pin
// (both R4 spill causes avoided).
__global__ __launch_bounds__(1024) void attn_fused(
    const unsigned short* __restrict__ q, const unsigned short* __restrict__ k_,
    const unsigned short* __restrict__ v_,
    const float* __restrict__ qrk, const float* __restrict__ rqk,
    const float* __restrict__ rel_v,
    const int* __restrict__ start_nodes, const int* __restrict__ end_nodes,
    unsigned short* __restrict__ attn)
{
    __shared__ unsigned short ell[128 * ELLSTRIDE];   // 18 KB
    __shared__ int cnt[128];
    const int bi  = blockIdx.x;          // 512 blocks
    const int xcd = bi & 7;
    const int loc = bi >> 3;             // 0..63
    const int bh  = xcd * 4 + (loc >> 4);
    const int dlo = (loc & 15) << 7;     // 128-dst window base
    const int t   = threadIdx.x;

    if (t < 128) cnt[t] = 0;
    __syncthreads();

    // ---- scan phase: one pass over the 8 underlying edge lists ----
    const int base_idx = bh * (R_ * S_);
    for (int f = t * 2; f < R_ * S_; f += 2048) {    // 8 iterations, r=0..7
        int r = f >> 11;                              // wave-uniform
        int s = f & (S_ - 1);                         // even
        int idx = base_idx + (r << 11) + s;
        int2 sn2 = *(const int2*)&start_nodes[idx];
        int2 en2 = *(const int2*)&end_nodes[idx];
        #pragma unroll
        for (int u = 0; u < 2; ++u) {
            int sn = u ? sn2.y : sn2.x;
            if (sn == -1) continue;                   // padded edge (both dirs)
            int en = u ? en2.y : en2.x;
            if (r >= 1) {                             // dir A: r2=r (r2=0 masked)
                unsigned rel = (unsigned)(en - dlo);
                if (rel < 128u) {
                    int pos = atomicAdd(&cnt[rel], 1);
                    if (pos < ELLCAP)
                        ell[rel * ELLSTRIDE + pos] = (unsigned short)((r << 11) | sn);
                }
            }
            {                                         // dir B: r2=r+8
                unsigned rel = (unsigned)(sn - dlo);
                if (rel < 128u) {
                    int pos = atomicAdd(&cnt[rel], 1);
                    if (pos < ELLCAP)
                        ell[rel * ELLSTRIDE + pos] = (unsigned short)(((r + 8) << 11) | en);
                }
            }
        }
    }
    __syncthreads();

    // ---- gather phase: group g of wave w owns dst dlo + w*8 + g ----
    const int w    = t >> 6;
    const int lane = t & 63;
    const int g    = lane >> 3;          // group (dst) within wave
    const int sub  = lane & 7;           // dk chunk (8 elems)
    const int dl   = w * 8 + g;          // 0..127
    const int dst  = dlo + dl;
    const int h    = bh & 7;
    const size_t node_base = ((size_t)bh << 11);
    const float* qrk_bh = qrk + (node_base << 4);
    const float* rqk_bh = rqk + (node_base << 4);
    const float* rvh    = rel_v + ((size_t)(h << 4) << 6);   // [16][64] f32

    ushort8_t q8 = *(const ushort8_t*)&q[((node_base + dst) << 6) + sub * 8];
    float qv[8];
    #pragma unroll
    for (int i = 0; i < 8; ++i) qv[i] = bf2f(q8[i]);
    const float* qrow = qrk_bh + ((size_t)dst << 4);

    int n = cnt[dl];
    if (n > ELLCAP) n = ELLCAP;
    int nmax = n;
    nmax = max(nmax, __shfl_xor(nmax, 8));
    nmax = max(nmax, __shfl_xor(nmax, 16));
    nmax = max(nmax, __shfl_xor(nmax, 32));

    const unsigned short* er = &ell[dl * ELLSTRIDE];

    float den = 0.f;
    float o[8] = {};

    // prologue: edge-0 data issue + edge-1 index in register
    int d1 = er[1];
    {
        int d0 = er[0];
        bool v0 = 0 < n;
        int ki0 = v0 ? (d0 & (S_ - 1)) : 0;
        int r20 = v0 ? ((d0 >> 11) & 15) : 0;
        // fallthrough into loop state below
        d1 = d1;  // keep
        // current stage regs:
        // (declared after to keep names simple)
        ;
        // load stage 0
        // (placed outside block via variables below)
        // -- see loop state init --
        // NOTE: code continues below
        // (we initialize named stage vars here)
        // ------------------------------------
        // stage vars
        // ------------------------------------
        // (HIP requires declarations outside this scope)
        (void)ki0; (void)r20;
    }
    int d0 = er[0];
    bool v0 = 0 < n;
    int ki = v0 ? (d0 & (S_ - 1)) : 0;
    int r2 = v0 ? ((d0 >> 11) & 15) : 0;
    ushort8_t k8 = *(const ushort8_t*)&k_[((node_base + ki) << 6) + sub * 8];
    ushort8_t v8 = *(const ushort8_t*)&v_[((node_base + ki) << 6) + sub * 8];
    float tb0 = qrow[r2] + rqk_bh[((size_t)ki << 4) + r2];
    float tb = v0 ? tb0 : -1e30f;

    for (int j = 0; j < nmax; ++j) {
        // fetch edge j+2 index (row padded to 72: j+2 <= 65 safe)
        int d2 = er[j + 2];
        // issue edge j+1 data from in-register d1 (no LDS dependency)
        bool vn = (j + 1) < n;
        int kin = vn ? (d1 & (S_ - 1)) : 0;
        int r2n = vn ? ((d1 >> 11) & 15) : 0;
        ushort8_t k8n = *(const ushort8_t*)&k_[((node_base + kin) << 6) + sub * 8];
        ushort8_t v8n = *(const ushort8_t*)&v_[((node_base + kin) << 6) + sub * 8];
        float tbs = qrow[r2n] + rqk_bh[((size_t)kin << 4) + r2n];
        float tbn = vn ? tbs : -1e30f;

        // compute edge j (tb=-1e30 for invalid -> exp()==0, no valid flag)
        float p = 0.f;
        #pragma unroll
        for (int i = 0; i < 8; ++i)
            p = fmaf(bf2f(k8[i]), qv[i], p);
        p += __shfl_xor(p, 1);
        p += __shfl_xor(p, 2);
        p += __shfl_xor(p, 4);
        float sf = __expf(fmaf(p, SCALE_, tb));
        const float* rvp = rvh + (r2 << 6) + sub * 8;
        f32x4 rv0 = *(const f32x4*)rvp;
        f32x4 rv1 = *(const f32x4*)(rvp + 4);
        den += sf;
        #pragma unroll
        for (int i = 0; i < 4; ++i)
            o[i] = fmaf(sf, bf2f(v8[i]) + rv0[i], o[i]);
        #pragma unroll
        for (int i = 0; i < 4; ++i)
            o[4 + i] = fmaf(sf, bf2f(v8[4 + i]) + rv1[i], o[4 + i]);

        // rotate pipeline
        k8 = k8n; v8 = v8n; tb = tbn; r2 = r2n; d1 = d2;
    }

    // epilogue: den/o complete per-lane (sf uniform in-group), no reduce
    float inv = (den > 0.f) ? 1.0f / den : 0.f;
    ushort8_t r;
    #pragma unroll
    for (int i = 0; i < 8; ++i) r[i] = f2bf(o[i] * inv);
    *(ushort8_t*)&attn[((node_base + dst) << 6) + sub * 8] = r;
}

extern "C" void kernel_launch(void* const* d_in, const int* in_sizes, int n_in,
                              void* d_out, int out_size, void* d_ws, size_t ws_size,
                              hipStream_t stream) {
    const float* query = (const float*)d_in[0];
    const float* key   = (const float*)d_in[1];
    const float* value = (const float*)d_in[2];
    const int* start_nodes = (const int*)d_in[3];
    const int* end_nodes   = (const int*)d_in[4];
    const float* rel_q = (const float*)d_in[5];
    const float* rel_k = (const float*)d_in[6];
    const float* rel_v = (const float*)d_in[7];
    const float* Wq = (const float*)d_in[8];
    const float* bq = (const float*)d_in[9];
    const float* Wk = (const float*)d_in[10];
    const float* bk = (const float*)d_in[11];
    const float* Wv = (const float*)d_in[12];
    const float* bv = (const float*)d_in[13];
    const float* Wo = (const float*)d_in[14];
    const float* bo = (const float*)d_in[15];
    float* out = (float*)d_out;

    const size_t NQ = (size_t)B_ * H_ * S_ * DK_;   // 4,194,304
    const size_t NW = (size_t)D_ * D_;              // 262,144
    unsigned short* p = (unsigned short*)d_ws;
    unsigned short* q    = p;          p += NQ;
    unsigned short* k    = p;          p += NQ;
    unsigned short* v    = p;          p += NQ;
    unsigned short* attn = p;          p += NQ;
    unsigned short* wqb  = p;          p += NW;
    unsigned short* wkb  = p;          p += NW;
    unsigned short* wvb  = p;          p += NW;
    unsigned short* wob  = p;          p += NW;
    float* qrk = (float*)p;            // 2 x 1M f32 = 8 MB
    float* rqk = qrk + ((size_t)1 << 20);

    // 1) W converts only (qkv conversion fused into GEMM1's A-staging)
    prepW<<<1024, 256, 0, stream>>>(Wq, Wk, Wv, Wo, wqb, wkb, wvb, wob);

    // 2) fused QKV projection, A read as f32 + converted in-kernel (pipelined)
    dim3 ggrid(B_ * S_ / 128, D_ / 128, 3);
    gemm_bf16<128, 1><<<ggrid, 256, 0, stream>>>(
        query, key, value, wqb, wkb, wvb, bq, bk, bv, q, k, v, nullptr, 0);

    // 3) rank-1 score-term tables via MFMA (q.rel_k, rel_q.k), prescaled by 1/24
    rel_dots<<<512, 256, 0, stream>>>(q, k, rel_q, rel_k, qrk, rqk);

    // 4) fused ELL-build + attention (half-scan + depth-2 index prefetch)
    attn_fused<<<512, 1024, 0, stream>>>(q, k, v, qrk, rqk, rel_v,
                                         start_nodes, end_nodes, attn);

    // 5) output projection (128x64 tiles -> 512 blocks, fp32 out)
    dim3 ogrid(B_ * S_ / 128, D_ / 64, 1);
    gemm_bf16<64, 0><<<ogrid, 256, 0, stream>>>(
        attn, attn, attn, wob, wob, wob, bo, bo, bo,
        nullptr, nullptr, nullptr, out, 1);
}

// Round 9
// 198.660 us; speedup vs baseline: 1.6355x; 1.0163x over previous
//
#include <hip/hip_runtime.h>
#include <math.h>

// Problem constants (fixed by reference): B=4, S=2048, D=512, H=8, R=8, dk=64
#define B_ 4
#define S_ 2048
#define D_ 512
#define H_ 8
#define R_ 8
#define DK_ 64
#define NEDGE (B_*H_*2*R_*S_)   // 1,048,576
#define EPB   (2*R_*S_)         // 32768 edge slots per (b,h)
#define ELLCAP 64               // max in-degree slots; Poisson(15) tail ~2e-8
#define ELLSTRIDE 72            // padded row stride (bank-spread + depth-2 prefetch slack)
#define SCALE_ (1.0f/24.0f)     // 1/(3*sqrt(dk))

typedef __attribute__((ext_vector_type(8))) short bf16x8;
typedef __attribute__((ext_vector_type(8))) unsigned short ushort8_t;
typedef __attribute__((ext_vector_type(4))) float f32x4;

#define AS1q const __attribute__((address_space(1)))
#define AS3q __attribute__((address_space(3)))

__device__ inline unsigned short f2bf(float f) {
    unsigned u = __builtin_bit_cast(unsigned, f);
    u += 0x7fffu + ((u >> 16) & 1u);   // RNE (no NaN inputs here)
    return (unsigned short)(u >> 16);
}
__device__ inline float bf2f(unsigned short u) {
    return __builtin_bit_cast(float, ((unsigned)u) << 16);
}
// HW packed f32->bf16 (RNE), per T12 recipe (no builtin on gfx950)
__device__ inline unsigned cvtpk(float lo, float hi) {
    unsigned r;
    asm("v_cvt_pk_bf16_f32 %0,%1,%2" : "=v"(r) : "v"(lo), "v"(hi));
    return r;
}

// ---------------- prep: W converts only (qkv conversion fused into GEMM1) ---
__global__ __launch_bounds__(256) void prepW(
    const float* __restrict__ Wq, const float* __restrict__ Wk,
    const float* __restrict__ Wv, const float* __restrict__ Wo,
    unsigned short* __restrict__ wqb, unsigned short* __restrict__ wkb,
    unsigned short* __restrict__ wvb, unsigned short* __restrict__ wob)
{
    int bid = blockIdx.x;              // 1024 blocks, 256 per matrix
    int z = bid >> 8;
    const float* x = (z == 0) ? Wq : (z == 1) ? Wk : (z == 2) ? Wv : Wo;
    unsigned short* y = (z == 0) ? wqb : (z == 1) ? wkb : (z == 2) ? wvb : wob;
    size_t i = ((size_t)(bid & 255) * 256 + threadIdx.x) * 4;
    float4 v = *(const float4*)&x[i];
    *(ushort4*)&y[i] = make_ushort4(f2bf(v.x), f2bf(v.y), f2bf(v.z), f2bf(v.w));
}

// ---------------- bf16 GEMM, m97-style ---------------------------------------
// AF32=1: A fp32 row-major, conversion fused; A-stage software-pipelined (T14):
// regs for step kk loaded AFTER barrier1 of step kk-64 (latency hides under
// compute, drains at trailing barrier). cvt_pk + ds_write into the SAME
// XOR-swizzled layout the gload_lds path makes: LDS[r][c] = global[r][c^(r&7)].
// AF32=0: A bf16 via global_load_lds (optionally bhsd, for GEMM2).
// B (weights) always bf16 via global_load_lds.
// R9: gemm1 instantiated at TN=64 (wave tile 64x32) -> 1536 blocks / 6144
// waves: R8 showed TN=128's 768-block grid capped occupancy at 13% with
// MfmaUtil 10% (latency-bound, both pipes idle).
template<int TN, int AF32>
__global__ __launch_bounds__(256) void gemm_bf16(
    const void* A0, const void* A1, const void* A2,
    const unsigned short* __restrict__ W0, const unsigned short* __restrict__ W1,
    const unsigned short* __restrict__ W2,
    const float* __restrict__ bi0, const float* __restrict__ bi1, const float* __restrict__ bi2,
    unsigned short* __restrict__ C0, unsigned short* __restrict__ C1,
    unsigned short* __restrict__ C2,
    float* __restrict__ Cf, int a_bhsd)
{
    constexpr int NFR = TN / 32;           // B frags per wave (4 or 2)
    __shared__ unsigned short As[128 * 64];
    __shared__ unsigned short Bs[TN * 64];
    const int z = blockIdx.z;
    const void* Av = (z == 0) ? A0 : (z == 1) ? A1 : A2;
    const unsigned short* W = (z == 0) ? W0 : (z == 1) ? W1 : W2;
    const float* bias        = (z == 0) ? bi0 : (z == 1) ? bi1 : bi2;
    unsigned short* C        = (z == 0) ? C0 : (z == 1) ? C1 : C2;

    const int t    = threadIdx.x;
    const int lane = t & 63;
    const int w    = t >> 6;
    const int wm   = w >> 1, wn = w & 1;
    const int m0   = blockIdx.x * 128;
    const int n0   = blockIdx.y * TN;

    const int lr    = lane >> 3;           // row within 8-row stage chunk
    const int cglob = (lane & 7) ^ lr;     // swizzled global source chunk

    f32x4 acc[4][NFR] = {};
    f32x4 xa[4][2];                        // AF32 staged A regs (32 VGPR)

    if constexpr (AF32) {
        const float* Af = (const float*)Av;
        #pragma unroll
        for (int i = 0; i < 4; ++i) {
            int m = m0 + w * 32 + i * 8 + lr;
            const float* ga = Af + (size_t)m * D_ + cglob * 8;
            xa[i][0] = *(const f32x4*)ga;
            xa[i][1] = *(const f32x4*)(ga + 4);
        }
    }

    for (int kk = 0; kk < D_; kk += 64) {
        if constexpr (AF32) {
            // write staged regs (loaded last iter, drained by trailing barrier)
            #pragma unroll
            for (int i = 0; i < 4; ++i) {
                int rowl = w * 32 + i * 8;
                unsigned pk0 = cvtpk(xa[i][0][0], xa[i][0][1]);
                unsigned pk1 = cvtpk(xa[i][0][2], xa[i][0][3]);
                unsigned pk2 = cvtpk(xa[i][1][0], xa[i][1][1]);
                unsigned pk3 = cvtpk(xa[i][1][2], xa[i][1][3]);
                *(uint4*)&As[(rowl + lr) * 64 + (lane & 7) * 8] =
                    make_uint4(pk0, pk1, pk2, pk3);
            }
        } else {
            const unsigned short* A = (const unsigned short*)Av;
            #pragma unroll
            for (int i = 0; i < 4; ++i) {
                int rowl = w * 32 + i * 8;         // wave-uniform LDS row base
                int m = m0 + rowl + lr;
                const unsigned short* ga;
                if (a_bhsd) {
                    int b = m >> 11, s = m & (S_ - 1), h = kk >> 6;
                    ga = A + ((((size_t)b * H_ + h) * S_ + s) << 6) + cglob * 8;
                } else {
                    ga = A + (size_t)m * D_ + kk + cglob * 8;
                }
                __builtin_amdgcn_global_load_lds((AS1q unsigned*)ga,
                    (AS3q unsigned*)(As + rowl * 64), 16, 0, 0);
            }
        }
        #pragma unroll
        for (int i = 0; i < TN / 32; ++i) {
            int rowl = w * (TN / 4) + i * 8;
            const unsigned short* gb =
                W + (size_t)(n0 + rowl + lr) * D_ + kk + cglob * 8;
            __builtin_amdgcn_global_load_lds((AS1q unsigned*)gb,
                (AS3q unsigned*)(Bs + rowl * 64), 16, 0, 0);
        }
        __syncthreads();

        if constexpr (AF32) {
            // issue NEXT K-step's A loads; latency hides under compute below
            if (kk + 64 < D_) {
                const float* Af = (const float*)Av;
                #pragma unroll
                for (int i = 0; i < 4; ++i) {
                    int m = m0 + w * 32 + i * 8 + lr;
                    const float* ga = Af + (size_t)m * D_ + (kk + 64) + cglob * 8;
                    xa[i][0] = *(const f32x4*)ga;
                    xa[i][1] = *(const f32x4*)(ga + 4);
                }
            }
        }

        #pragma unroll
        for (int ks = 0; ks < 64; ks += 32) {
            const int c0 = ks >> 3;            // 0 or 4
            bf16x8 af[4], bfr[NFR];
            #pragma unroll
            for (int mi = 0; mi < 4; ++mi) {
                int row = wm * 64 + mi * 16 + (lane & 15);
                int cp  = (c0 + (lane >> 4)) ^ (lane & 7);
                af[mi] = *(const bf16x8*)&As[row * 64 + cp * 8];
            }
            #pragma unroll
            for (int nj = 0; nj < NFR; ++nj) {
                int row = wn * (TN / 2) + nj * 16 + (lane & 15);
                int cp  = (c0 + (lane >> 4)) ^ (lane & 7);
                bfr[nj] = *(const bf16x8*)&Bs[row * 64 + cp * 8];
            }
            #pragma unroll
            for (int mi = 0; mi < 4; ++mi)
                #pragma unroll
                for (int nj = 0; nj < NFR; ++nj)
                    acc[mi][nj] = __builtin_amdgcn_mfma_f32_16x16x32_bf16(af[mi], bfr[nj], acc[mi][nj], 0, 0, 0);
        }
        __syncthreads();
    }

    // epilogue: C/D layout col = lane&15, row = (lane>>4)*4 + reg
    #pragma unroll
    for (int mi = 0; mi < 4; ++mi) {
        #pragma unroll
        for (int nj = 0; nj < NFR; ++nj) {
            #pragma unroll
            for (int r = 0; r < 4; ++r) {
                int m = m0 + wm * 64 + mi * 16 + (lane >> 4) * 4 + r;
                int n = n0 + wn * (TN / 2) + nj * 16 + (lane & 15);
                float val = acc[mi][nj][r] + bias[n];
                if (Cf) {
                    Cf[(size_t)m * D_ + n] = val;
                } else {
                    int b = m >> 11, s = m & (S_ - 1);
                    int h = n >> 6,  d = n & 63;
                    C[((((size_t)b * H_ + h) * S_ + s) << 6) + d] = f2bf(val);
                }
            }
        }
    }
}

// ---------------- rank-1 score-term tables via MFMA -------------------------
// qrk[node][r2] = (q[node].rel_k[h][r2])/24 ; rqk[node][r2] = (rel_q[h][r2].k[node])/24
__global__ __launch_bounds__(256) void rel_dots(
    const unsigned short* __restrict__ q, const unsigned short* __restrict__ k_,
    const float* __restrict__ rel_q, const float* __restrict__ rel_k,
    float* __restrict__ qrk, float* __restrict__ rqk)
{
    const int t    = threadIdx.x;
    const int lane = t & 63;
    const int w    = t >> 6;
    const int n0   = blockIdx.x * 128 + w * 32;   // wave's 32-node base (never crosses bh)
    const int h    = (n0 >> 11) & 7;
    const int r2   = lane & 15;
    const int ch   = lane >> 4;                   // 0..3: 8-elem k-chunk

    // B fragments for both k-halves, both tables (f32 -> bf16 in-register)
    bf16x8 bk2[2], bq2[2];
    #pragma unroll
    for (int ks = 0; ks < 2; ++ks) {
        const float* pk = rel_k + (((h << 4) + r2) << 6) + ks * 32 + ch * 8;
        const float* pq = rel_q + (((h << 4) + r2) << 6) + ks * 32 + ch * 8;
        f32x4 k0 = *(const f32x4*)pk, k1 = *(const f32x4*)(pk + 4);
        f32x4 q0 = *(const f32x4*)pq, q1 = *(const f32x4*)(pq + 4);
        bf16x8 bk, bq;
        #pragma unroll
        for (int i = 0; i < 4; ++i) {
            bk[i]     = (short)f2bf(k0[i]);
            bk[4 + i] = (short)f2bf(k1[i]);
            bq[i]     = (short)f2bf(q0[i]);
            bq[4 + i] = (short)f2bf(q1[i]);
        }
        bk2[ks] = bk; bq2[ks] = bq;
    }

    f32x4 aq[2] = {{0.f,0.f,0.f,0.f},{0.f,0.f,0.f,0.f}};
    f32x4 ak[2] = {{0.f,0.f,0.f,0.f},{0.f,0.f,0.f,0.f}};
    #pragma unroll
    for (int mi = 0; mi < 2; ++mi) {
        int m = n0 + mi * 16 + r2;               // A-frag row = lane&15
        #pragma unroll
        for (int ks = 0; ks < 2; ++ks) {
            bf16x8 aqf = *(const bf16x8*)&q [((size_t)m << 6) + ks * 32 + ch * 8];
            bf16x8 akf = *(const bf16x8*)&k_[((size_t)m << 6) + ks * 32 + ch * 8];
            aq[mi] = __builtin_amdgcn_mfma_f32_16x16x32_bf16(aqf, bk2[ks], aq[mi], 0, 0, 0);
            ak[mi] = __builtin_amdgcn_mfma_f32_16x16x32_bf16(akf, bq2[ks], ak[mi], 0, 0, 0);
        }
    }
    #pragma unroll
    for (int mi = 0; mi < 2; ++mi) {
        #pragma unroll
        for (int r = 0; r < 4; ++r) {
            int m = n0 + mi * 16 + (ch << 2) + r;
            qrk[((size_t)m << 4) + r2] = aq[mi][r] * SCALE_;
            rqk[((size_t)m << 4) + r2] = ak[mi][r] * SCALE_;
        }
    }
}

// ---------------- fused ELL-build + score+softmax+aggregate -----------------
// R8 scan: iterate r=0..7 (8 iters) — one int2 pair read per underlying edge,
// claiming BOTH directions (r2=r: dst=en,ki=sn for r>=1; r2=r+8: dst=sn,ki=en).
// R8 gather: depth-2 INDEX prefetch — d1=er[j+1] in-register from the previous
// iteration so k8n/v8n/tbn L2 loads issue at the TOP of iter j with no LDS
// dependency; er[j+2] fetched in parallel.
__global__ __launch_bounds__(1024) void attn_fused(
    const unsigned short* __restrict__ q, const unsigned short* __restrict__ k_,
    const unsigned short* __restrict__ v_,
    const float* __restrict__ qrk, const float* __restrict__ rqk,
    const float* __restrict__ rel_v,
    const int* __restrict__ start_nodes, const int* __restrict__ end_nodes,
    unsigned short* __restrict__ attn)
{
    __shared__ unsigned short ell[128 * ELLSTRIDE];   // 18 KB
    __shared__ int cnt[128];
    const int bi  = blockIdx.x;          // 512 blocks
    const int xcd = bi & 7;
    const int loc = bi >> 3;             // 0..63
    const int bh  = xcd * 4 + (loc >> 4);
    const int dlo = (loc & 15) << 7;     // 128-dst window base
    const int t   = threadIdx.x;

    if (t < 128) cnt[t] = 0;
    __syncthreads();

    // ---- scan phase: one pass over the 8 underlying edge lists ----
    const int base_idx = bh * (R_ * S_);
    for (int f = t * 2; f < R_ * S_; f += 2048) {    // 8 iterations, r=0..7
        int r = f >> 11;                              // wave-uniform
        int s = f & (S_ - 1);                         // even
        int idx = base_idx + (r << 11) + s;
        int2 sn2 = *(const int2*)&start_nodes[idx];
        int2 en2 = *(const int2*)&end_nodes[idx];
        #pragma unroll
        for (int u = 0; u < 2; ++u) {
            int sn = u ? sn2.y : sn2.x;
            if (sn == -1) continue;                   // padded edge (both dirs)
            int en = u ? en2.y : en2.x;
            if (r >= 1) {                             // dir A: r2=r (r2=0 masked)
                unsigned rel = (unsigned)(en - dlo);
                if (rel < 128u) {
                    int pos = atomicAdd(&cnt[rel], 1);
                    if (pos < ELLCAP)
                        ell[rel * ELLSTRIDE + pos] = (unsigned short)((r << 11) | sn);
                }
            }
            {                                         // dir B: r2=r+8
                unsigned rel = (unsigned)(sn - dlo);
                if (rel < 128u) {
                    int pos = atomicAdd(&cnt[rel], 1);
                    if (pos < ELLCAP)
                        ell[rel * ELLSTRIDE + pos] = (unsigned short)(((r + 8) << 11) | en);
                }
            }
        }
    }
    __syncthreads();

    // ---- gather phase: group g of wave w owns dst dlo + w*8 + g ----
    const int w    = t >> 6;
    const int lane = t & 63;
    const int g    = lane >> 3;          // group (dst) within wave
    const int sub  = lane & 7;           // dk chunk (8 elems)
    const int dl   = w * 8 + g;          // 0..127
    const int dst  = dlo + dl;
    const int h    = bh & 7;
    const size_t node_base = ((size_t)bh << 11);
    const float* qrk_bh = qrk + (node_base << 4);
    const float* rqk_bh = rqk + (node_base << 4);
    const float* rvh    = rel_v + ((size_t)(h << 4) << 6);   // [16][64] f32

    ushort8_t q8 = *(const ushort8_t*)&q[((node_base + dst) << 6) + sub * 8];
    float qv[8];
    #pragma unroll
    for (int i = 0; i < 8; ++i) qv[i] = bf2f(q8[i]);
    const float* qrow = qrk_bh + ((size_t)dst << 4);

    int n = cnt[dl];
    if (n > ELLCAP) n = ELLCAP;
    int nmax = n;
    nmax = max(nmax, __shfl_xor(nmax, 8));
    nmax = max(nmax, __shfl_xor(nmax, 16));
    nmax = max(nmax, __shfl_xor(nmax, 32));

    const unsigned short* er = &ell[dl * ELLSTRIDE];

    float den = 0.f;
    float o[8] = {};

    // prologue: edge-0 data issue + edge-1 index in register
    int d1 = er[1];
    int d0 = er[0];
    bool v0 = 0 < n;
    int ki = v0 ? (d0 & (S_ - 1)) : 0;
    int r2 = v0 ? ((d0 >> 11) & 15) : 0;
    ushort8_t k8 = *(const ushort8_t*)&k_[((node_base + ki) << 6) + sub * 8];
    ushort8_t v8 = *(const ushort8_t*)&v_[((node_base + ki) << 6) + sub * 8];
    float tb0 = qrow[r2] + rqk_bh[((size_t)ki << 4) + r2];
    float tb = v0 ? tb0 : -1e30f;

    for (int j = 0; j < nmax; ++j) {
        // fetch edge j+2 index (row padded to 72: j+2 <= 65 safe)
        int d2 = er[j + 2];
        // issue edge j+1 data from in-register d1 (no LDS dependency)
        bool vn = (j + 1) < n;
        int kin = vn ? (d1 & (S_ - 1)) : 0;
        int r2n = vn ? ((d1 >> 11) & 15) : 0;
        ushort8_t k8n = *(const ushort8_t*)&k_[((node_base + kin) << 6) + sub * 8];
        ushort8_t v8n = *(const ushort8_t*)&v_[((node_base + kin) << 6) + sub * 8];
        float tbs = qrow[r2n] + rqk_bh[((size_t)kin << 4) + r2n];
        float tbn = vn ? tbs : -1e30f;

        // compute edge j (tb=-1e30 for invalid -> exp()==0, no valid flag)
        float p = 0.f;
        #pragma unroll
        for (int i = 0; i < 8; ++i)
            p = fmaf(bf2f(k8[i]), qv[i], p);
        p += __shfl_xor(p, 1);
        p += __shfl_xor(p, 2);
        p += __shfl_xor(p, 4);
        float sf = __expf(fmaf(p, SCALE_, tb));
        const float* rvp = rvh + (r2 << 6) + sub * 8;
        f32x4 rv0 = *(const f32x4*)rvp;
        f32x4 rv1 = *(const f32x4*)(rvp + 4);
        den += sf;
        #pragma unroll
        for (int i = 0; i < 4; ++i)
            o[i] = fmaf(sf, bf2f(v8[i]) + rv0[i], o[i]);
        #pragma unroll
        for (int i = 0; i < 4; ++i)
            o[4 + i] = fmaf(sf, bf2f(v8[4 + i]) + rv1[i], o[4 + i]);

        // rotate pipeline
        k8 = k8n; v8 = v8n; tb = tbn; r2 = r2n; d1 = d2;
    }

    // epilogue: den/o complete per-lane (sf uniform in-group), no reduce
    float inv = (den > 0.f) ? 1.0f / den : 0.f;
    ushort8_t r;
    #pragma unroll
    for (int i = 0; i < 8; ++i) r[i] = f2bf(o[i] * inv);
    *(ushort8_t*)&attn[((node_base + dst) << 6) + sub * 8] = r;
}

extern "C" void kernel_launch(void* const* d_in, const int* in_sizes, int n_in,
                              void* d_out, int out_size, void* d_ws, size_t ws_size,
                              hipStream_t stream) {
    const float* query = (const float*)d_in[0];
    const float* key   = (const float*)d_in[1];
    const float* value = (const float*)d_in[2];
    const int* start_nodes = (const int*)d_in[3];
    const int* end_nodes   = (const int*)d_in[4];
    const float* rel_q = (const float*)d_in[5];
    const float* rel_k = (const float*)d_in[6];
    const float* rel_v = (const float*)d_in[7];
    const float* Wq = (const float*)d_in[8];
    const float* bq = (const float*)d_in[9];
    const float* Wk = (const float*)d_in[10];
    const float* bk = (const float*)d_in[11];
    const float* Wv = (const float*)d_in[12];
    const float* bv = (const float*)d_in[13];
    const float* Wo = (const float*)d_in[14];
    const float* bo = (const float*)d_in[15];
    float* out = (float*)d_out;

    const size_t NQ = (size_t)B_ * H_ * S_ * DK_;   // 4,194,304
    const size_t NW = (size_t)D_ * D_;              // 262,144
    unsigned short* p = (unsigned short*)d_ws;
    unsigned short* q    = p;          p += NQ;
    unsigned short* k    = p;          p += NQ;
    unsigned short* v    = p;          p += NQ;
    unsigned short* attn = p;          p += NQ;
    unsigned short* wqb  = p;          p += NW;
    unsigned short* wkb  = p;          p += NW;
    unsigned short* wvb  = p;          p += NW;
    unsigned short* wob  = p;          p += NW;
    float* qrk = (float*)p;            // 2 x 1M f32 = 8 MB
    float* rqk = qrk + ((size_t)1 << 20);

    // 1) W converts only (qkv conversion fused into GEMM1's A-staging)
    prepW<<<1024, 256, 0, stream>>>(Wq, Wk, Wv, Wo, wqb, wkb, wvb, wob);

    // 2) fused QKV projection, A f32 + converted in-kernel (pipelined).
    //    TN=64: 1536 blocks / 6144 waves (R8: TN=128's 768 blocks -> 13% occ)
    dim3 ggrid(B_ * S_ / 128, D_ / 64, 3);
    gemm_bf16<64, 1><<<ggrid, 256, 0, stream>>>(
        query, key, value, wqb, wkb, wvb, bq, bk, bv, q, k, v, nullptr, 0);

    // 3) rank-1 score-term tables via MFMA (q.rel_k, rel_q.k), prescaled by 1/24
    rel_dots<<<512, 256, 0, stream>>>(q, k, rel_q, rel_k, qrk, rqk);

    // 4) fused ELL-build + attention (half-scan + depth-2 index prefetch)
    attn_fused<<<512, 1024, 0, stream>>>(q, k, v, qrk, rqk, rel_v,
                                         start_nodes, end_nodes, attn);

    // 5) output projection (128x64 tiles -> 512 blocks, fp32 out)
    dim3 ogrid(B_ * S_ / 128, D_ / 64, 1);
    gemm_bf16<64, 0><<<ogrid, 256, 0, stream>>>(
        attn, attn, attn, wob, wob, wob, bo, bo, bo,
        nullptr, nullptr, nullptr, out, 1);
}